// Round 1
// baseline (1567.503 us; speedup 1.0000x reference)
//
#include <hip/hip_runtime.h>
#include <hip/hip_bf16.h>

#define NN 100000
#define NE 1600000
#define DIM 128
#define NBLK ((NN + 255) / 256)   // 391

using bf16 = __hip_bfloat16;
using bf162 = __hip_bfloat162;

// ---------- dtype helpers ----------
__device__ __forceinline__ float to_f(const float v) { return v; }
__device__ __forceinline__ float to_f(const bf16 v) { return __bfloat162float(v); }

__device__ __forceinline__ float4 ld4(const float* p) {
    return *reinterpret_cast<const float4*>(p);
}
__device__ __forceinline__ float4 ld4(const bf16* p) {
    const bf162* q = reinterpret_cast<const bf162*>(p);
    float2 a = __bfloat1622float2(q[0]);
    float2 b = __bfloat1622float2(q[1]);
    return make_float4(a.x, a.y, b.x, b.y);
}
__device__ __forceinline__ float2 ld2(const float* p) {
    return *reinterpret_cast<const float2*>(p);
}
__device__ __forceinline__ float2 ld2(const bf16* p) {
    return __bfloat1622float2(*reinterpret_cast<const bf162*>(p));
}
__device__ __forceinline__ void st1(float* p, float v) { *p = v; }
__device__ __forceinline__ void st1(bf16* p, float v) { *p = __float2bfloat16(v); }

// ---------- degree / normalization ----------
__global__ void count_deg_k(const int* __restrict__ dst, int* __restrict__ cnt) {
    int i = blockIdx.x * blockDim.x + threadIdx.x;   // grid = NE exactly
    atomicAdd(&cnt[dst[i]], 1);
}

__global__ void dinv_k(const int* __restrict__ cnt, float* __restrict__ dinv) {
    int i = blockIdx.x * blockDim.x + threadIdx.x;
    if (i < NN) dinv[i] = rsqrtf((float)cnt[i] + 1.0f);   // +1 self-loop
}

// ---------- CSR build: two-level exclusive scan + cursor fill ----------
__global__ void blocksum_k(const int* __restrict__ cnt, int* __restrict__ bsum) {
    __shared__ int s[256];
    int i = blockIdx.x * 256 + threadIdx.x;
    s[threadIdx.x] = (i < NN) ? cnt[i] : 0;
    __syncthreads();
    for (int off = 128; off > 0; off >>= 1) {
        if (threadIdx.x < off) s[threadIdx.x] += s[threadIdx.x + off];
        __syncthreads();
    }
    if (threadIdx.x == 0) bsum[blockIdx.x] = s[0];
}

__global__ void scan_bsum_k(const int* __restrict__ bsum, int* __restrict__ boff) {
    __shared__ int s[512];                           // 1 block of 512 covers NBLK=391
    int t = threadIdx.x;
    int v = (t < NBLK) ? bsum[t] : 0;
    s[t] = v;
    __syncthreads();
    for (int off = 1; off < 512; off <<= 1) {
        int tmp = (t >= off) ? s[t - off] : 0;
        __syncthreads();
        s[t] += tmp;
        __syncthreads();
    }
    if (t < NBLK) boff[t] = s[t] - v;                // exclusive
}

__global__ void scan_block_k(const int* __restrict__ cnt, const int* __restrict__ boff,
                             int* __restrict__ row_ptr, int* __restrict__ cursor) {
    __shared__ int s[256];
    int t = threadIdx.x, i = blockIdx.x * 256 + t;
    int v = (i < NN) ? cnt[i] : 0;
    s[t] = v;
    __syncthreads();
    for (int off = 1; off < 256; off <<= 1) {
        int tmp = (t >= off) ? s[t - off] : 0;
        __syncthreads();
        s[t] += tmp;
        __syncthreads();
    }
    if (i < NN) {
        int e = boff[blockIdx.x] + s[t] - v;         // global exclusive
        row_ptr[i] = e;
        cursor[i] = e;
    }
    if (i == NN - 1) row_ptr[NN] = NE;
}

__global__ void fill_k(const int* __restrict__ src, const int* __restrict__ dst,
                       int* __restrict__ cursor, int* __restrict__ csr_src) {
    int e = blockIdx.x * 256 + threadIdx.x;          // grid = NE exactly
    int d = dst[e];
    int pos = atomicAdd(&cursor[d], 1);
    csr_src[pos] = src[e];
}

// ---------- CSR gather: one wave per dst node, no atomics ----------
// v2: two edges in flight per wave (lane>>5 selects edge), float4 loads.
// Halves the serial per-edge dependency chain and the shfl count per edge.
// Inactive-lane tail handling is free: s=0/ns=0 init means a shfl past the
// chunk end contributes 0 (and loads row 0 harmlessly).
template <typename ST>
__global__ __launch_bounds__(256) void gather_k(const int* __restrict__ row_ptr,
                                                const int* __restrict__ csr_src,
                                                const float* __restrict__ dinv,
                                                const ST* __restrict__ h,
                                                float* __restrict__ agg) {
    int w = blockIdx.x * 4 + (threadIdx.x >> 6);     // node id; grid = NN/4 exactly
    if (w >= NN) return;
    int lane = threadIdx.x & 63;
    int eh = lane >> 5;                              // which of 2 concurrent edges
    int l  = lane & 31;                              // column group: cols l*4 .. l*4+3
    int beg = row_ptr[w], end = row_ptr[w + 1];
    float dd = dinv[w];
    float ax = 0.f, ay = 0.f, az = 0.f, aw = 0.f;
    for (int base = beg; base < end; base += 64) {
        int k = end - base;
        if (k > 64) k = 64;
        int s = 0;
        float ns = 0.f;
        if (lane < k) { s = csr_src[base + lane]; ns = dinv[s]; }
        for (int j = 0; j < k; j += 2) {
            int   sj = __shfl(s,  j + eh);
            float nj = __shfl(ns, j + eh);
            float4 hv = ld4(&h[(size_t)sj * DIM + l * 4]);  // 16B/lane, 512B/edge
            ax = fmaf(hv.x, nj, ax);
            ay = fmaf(hv.y, nj, ay);
            az = fmaf(hv.z, nj, az);
            aw = fmaf(hv.w, nj, aw);
        }
    }
    // combine the two half-wave partials (lane ^ 32)
    ax += __shfl_xor(ax, 32);
    ay += __shfl_xor(ay, 32);
    az += __shfl_xor(az, 32);
    aw += __shfl_xor(aw, 32);
    if (eh == 0) {
        reinterpret_cast<float4*>(&agg[(size_t)w * DIM])[l] =
            make_float4(ax * dd, ay * dd, az * dd, aw * dd);
    }
}

// ---------- atomic scatter (fallback for tiny ws) ----------
template <typename ST>
__global__ void scatter_k(const int* __restrict__ src, const int* __restrict__ dst,
                          const float* __restrict__ dinv, const ST* __restrict__ S,
                          float* __restrict__ agg) {
    int i = blockIdx.x * blockDim.x + threadIdx.x;   // grid = NE*32 exactly
    int e = i >> 5;
    int p = (i & 31) * 4;
    int s = src[e], d = dst[e];
    float nrm = dinv[s] * dinv[d];
    float4 hv = ld4(&S[(size_t)s * DIM + p]);
    float* ap = &agg[(size_t)d * DIM + p];
    atomicAdd(ap + 0, hv.x * nrm);
    atomicAdd(ap + 1, hv.y * nrm);
    atomicAdd(ap + 2, hv.z * nrm);
    atomicAdd(ap + 3, hv.w * nrm);
}

// ---------- fused GEMM: out = act((agg + S*dinv^2) @ W + b) ----------
// 8 rows per 256-thread block; agg/S/out may alias row-wise (in-place safe).
template <typename ST, typename OT, bool RELU>
__global__ __launch_bounds__(256) void gemm_fused_k(const float* agg, const ST* S,
                                                    const float* __restrict__ dinv,
                                                    const float* __restrict__ W,
                                                    const float* __restrict__ bias,
                                                    OT* out) {
    __shared__ float Ws[DIM * DIM];
    __shared__ float xs[8][DIM];
    __shared__ float bs[DIM];
    const int t = threadIdx.x;

#pragma unroll
    for (int i = 0; i < (DIM * DIM) / 256; ++i) Ws[t + i * 256] = W[t + i * 256];
    if (t < DIM) bs[t] = bias[t];

    const int r0 = blockIdx.x * 8;                   // grid = NN/8 exactly
#pragma unroll
    for (int i = 0; i < 4; ++i) {
        int idx = t + i * 256;
        int rr = idx >> 7, c = idx & 127;
        int r = r0 + rr;
        float di = dinv[r];
        size_t off = (size_t)r * DIM + c;
        xs[rr][c] = agg[off] + to_f(S[off]) * di * di;
    }
    __syncthreads();

    const int c  = t & 127;
    const int rb = (t >> 7) * 4;
    float a0 = 0.f, a1 = 0.f, a2 = 0.f, a3 = 0.f;
#pragma unroll 4
    for (int k = 0; k < DIM; ++k) {
        float w = Ws[k * DIM + c];
        a0 = fmaf(xs[rb + 0][k], w, a0);
        a1 = fmaf(xs[rb + 1][k], w, a1);
        a2 = fmaf(xs[rb + 2][k], w, a2);
        a3 = fmaf(xs[rb + 3][k], w, a3);
    }
    float b = bs[c];
    a0 += b; a1 += b; a2 += b; a3 += b;
    if (RELU) {
        a0 = fmaxf(a0, 0.f); a1 = fmaxf(a1, 0.f);
        a2 = fmaxf(a2, 0.f); a3 = fmaxf(a3, 0.f);
    }
    size_t o = (size_t)(r0 + rb) * DIM + c;
    st1(&out[o], a0);
    st1(&out[o + DIM], a1);
    st1(&out[o + 2 * DIM], a2);
    st1(&out[o + 3 * DIM], a3);
}

// ---------- tier-3 utilities ----------
__global__ void compress_k(const float* __restrict__ src, bf16* __restrict__ dst) {
    int i = blockIdx.x * blockDim.x + threadIdx.x;   // grid = NB/256 exactly
    dst[i] = __float2bfloat16(src[i]);
}
__global__ void decomp_k(float* __restrict__ dst, const bf16* __restrict__ src, int n) {
    int i = blockIdx.x * blockDim.x + threadIdx.x;
    if (i < n) dst[i] = __bfloat162float(src[i]);
}

// ---------- driver ----------
// ws layout (CSR mode, needs >= 9 MiB):
//   cnt     @ 0        (400 KB, int)
//   dinv    @ 512 KiB  (400 KB)
//   row_ptr @ 1 MiB    (400 KB)
//   cursor  @ 1.5 MiB  (400 KB)
//   bsum    @ 2 MiB    (1.6 KB), boff @ 2 MiB + 4 KB
//   csr_src @ 2.25 MiB (6.4 MB)
//   big     @ 9 MiB    (graph-1 H tiers)
// Fallback mode (ws < 9 MiB): cnt/dinv as above, big @ 1 MiB, atomic scatter.
extern "C" void kernel_launch(void* const* d_in, const int* in_sizes, int n_in,
                              void* d_out, int out_size, void* d_ws, size_t ws_size,
                              hipStream_t stream) {
    const float* W0 = (const float*)d_in[4];
    const float* b0 = (const float*)d_in[5];
    const float* W1 = (const float*)d_in[6];
    const float* b1 = (const float*)d_in[7];

    char* ws = (char*)d_ws;
    int*   cnt  = (int*)ws;
    float* dinv = (float*)(ws + (512u << 10));
    int* row_ptr = (int*)(ws + (1u << 20));
    int* cursor  = (int*)(ws + (3u << 19));
    int* bsum    = (int*)(ws + (2u << 20));
    int* boff    = (int*)(ws + (2u << 20) + 4096);
    int* csr_src = (int*)(ws + (9u << 18));          // 2.25 MiB

    const bool csr_ok = ws_size >= (9u << 20);
    char* big = csr_ok ? ws + (9u << 20) : ws + (1u << 20);
    size_t big_avail = ws_size - (csr_ok ? (9u << 20) : (1u << 20));

    const size_t NB = (size_t)NN * DIM;
    float* slot0 = (float*)d_out;
    float* slot1 = slot0 + NB;

    const int SG = (NE * 32) / 256;
    const int GG = NN / 8;
    const int CG = NE / 256;

    auto build = [&](const int* srcp, const int* dstp) {
        hipMemsetAsync(cnt, 0, NN * sizeof(int), stream);
        count_deg_k<<<CG, 256, 0, stream>>>(dstp, cnt);
        dinv_k<<<(NN + 255) / 256, 256, 0, stream>>>(cnt, dinv);
        if (!csr_ok) return;
        blocksum_k<<<NBLK, 256, 0, stream>>>(cnt, bsum);
        scan_bsum_k<<<1, 512, 0, stream>>>(bsum, boff);
        scan_block_k<<<NBLK, 256, 0, stream>>>(cnt, boff, row_ptr, cursor);
        fill_k<<<CG, 256, 0, stream>>>(srcp, dstp, cursor, csr_src);
    };
    auto agg_f = [&](const int* srcp, const int* dstp, const float* h, float* agg) {
        if (csr_ok) {
            gather_k<float><<<NN / 4, 256, 0, stream>>>(row_ptr, csr_src, dinv, h, agg);
        } else {
            hipMemsetAsync(agg, 0, NB * sizeof(float), stream);
            scatter_k<float><<<SG, 256, 0, stream>>>(srcp, dstp, dinv, h, agg);
        }
    };
    auto agg_b = [&](const int* srcp, const int* dstp, const bf16* h, float* agg) {
        if (csr_ok) {
            gather_k<bf16><<<NN / 4, 256, 0, stream>>>(row_ptr, csr_src, dinv, h, agg);
        } else {
            hipMemsetAsync(agg, 0, NB * sizeof(float), stream);
            scatter_k<bf16><<<SG, 256, 0, stream>>>(srcp, dstp, dinv, h, agg);
        }
    };

    // ================= graph 0 (h in slot1, result in slot0) =================
    {
        const float* x  = (const float*)d_in[0];
        const int*   ei = (const int*)d_in[1];
        build(ei, ei + NE);
        agg_f(ei, ei + NE, x, slot1);
        gemm_fused_k<float, float, true><<<GG, 256, 0, stream>>>(slot1, x, dinv, W0, b0, slot1);
        agg_f(ei, ei + NE, slot1, slot0);
        gemm_fused_k<float, float, false><<<GG, 256, 0, stream>>>(slot0, slot1, dinv, W1, b1, slot0);
    }

    // ================= graph 1 =================
    {
        const float* x  = (const float*)d_in[2];
        const int*   ei = (const int*)d_in[3];
        build(ei, ei + NE);

        if (big_avail >= NB * sizeof(float)) {
            // tier 1: fp32 H in ws
            float* H = (float*)big;
            agg_f(ei, ei + NE, x, H);
            gemm_fused_k<float, float, true><<<GG, 256, 0, stream>>>(H, x, dinv, W0, b0, H);
            agg_f(ei, ei + NE, H, slot1);
            gemm_fused_k<float, float, false><<<GG, 256, 0, stream>>>(slot1, H, dinv, W1, b1, slot1);
        } else if (big_avail >= NB * sizeof(bf16)) {
            // tier 2: bf16 H in ws
            bf16* H = (bf16*)big;
            agg_f(ei, ei + NE, x, slot1);
            gemm_fused_k<float, bf16, true><<<GG, 256, 0, stream>>>(slot1, x, dinv, W0, b0, H);
            agg_b(ei, ei + NE, H, slot1);
            gemm_fused_k<bf16, float, false><<<GG, 256, 0, stream>>>(slot1, H, dinv, W1, b1, slot1);
        } else {
            // tier 3: stash g0 as bf16 in slot1 low half, h1 as bf16 in slot1 high half
            bf16* g0b = (bf16*)slot1;
            bf16* h1b = (bf16*)((char*)slot1 + NB * sizeof(bf16));
            compress_k<<<(int)(NB / 256), 256, 0, stream>>>(slot0, g0b);
            agg_f(ei, ei + NE, x, slot0);
            gemm_fused_k<float, bf16, true><<<GG, 256, 0, stream>>>(slot0, x, dinv, W0, b0, h1b);
            agg_b(ei, ei + NE, h1b, slot0);
            gemm_fused_k<bf16, float, false><<<GG, 256, 0, stream>>>(slot0, h1b, dinv, W1, b1, slot0);
            // swap: slot0 (g1) -> slot1, decompress g0b -> slot0, descending chunks.
            float* stage;
            size_t C;
            if (csr_ok) { stage = (float*)csr_src; C = 1600000; }   // CSR dead now
            else {
                stage = (float*)big;
                C = (big_avail / sizeof(float)) & ~(size_t)255;
                if (C < 256) C = 256;
            }
            size_t a = NB;
            while (a > 0) {
                size_t len = (a >= C) ? C : a;
                a -= len;
                hipMemcpyAsync(stage, slot0 + a, len * sizeof(float),
                               hipMemcpyDeviceToDevice, stream);
                decomp_k<<<(int)((len + 255) / 256), 256, 0, stream>>>(slot0 + a, g0b + a, (int)len);
                hipMemcpyAsync(slot1 + a, stage, len * sizeof(float),
                               hipMemcpyDeviceToDevice, stream);
            }
        }
    }
}

// Round 2
// 1258.192 us; speedup vs baseline: 1.2458x; 1.2458x over previous
//
#include <hip/hip_runtime.h>
#include <hip/hip_bf16.h>

#define NN 100000
#define NE 1600000
#define DIM 128
#define NBLK ((NN + 255) / 256)   // 391

using bf16 = __hip_bfloat16;
using bf162 = __hip_bfloat162;

// ---------- dtype helpers ----------
__device__ __forceinline__ float to_f(const float v) { return v; }
__device__ __forceinline__ float to_f(const bf16 v) { return __bfloat162float(v); }

__device__ __forceinline__ float4 ld4(const float* p) {
    return *reinterpret_cast<const float4*>(p);
}
__device__ __forceinline__ float4 ld4(const bf16* p) {
    const bf162* q = reinterpret_cast<const bf162*>(p);
    float2 a = __bfloat1622float2(q[0]);
    float2 b = __bfloat1622float2(q[1]);
    return make_float4(a.x, a.y, b.x, b.y);
}
__device__ __forceinline__ float2 ld2(const float* p) {
    return *reinterpret_cast<const float2*>(p);
}
__device__ __forceinline__ float2 ld2(const bf16* p) {
    return __bfloat1622float2(*reinterpret_cast<const bf162*>(p));
}
__device__ __forceinline__ void st1(float* p, float v) { *p = v; }
__device__ __forceinline__ void st1(bf16* p, float v) { *p = __float2bfloat16(v); }
__device__ __forceinline__ void st4(float* p, float4 v) {
    *reinterpret_cast<float4*>(p) = v;
}
__device__ __forceinline__ void st4(bf16* p, float4 v) {
    bf162* q = reinterpret_cast<bf162*>(p);
    q[0] = __float22bfloat162_rn(make_float2(v.x, v.y));
    q[1] = __float22bfloat162_rn(make_float2(v.z, v.w));
}

// ---------- degree / normalization ----------
__global__ void count_deg_k(const int* __restrict__ dst, int* __restrict__ cnt) {
    int i = blockIdx.x * blockDim.x + threadIdx.x;   // grid = NE exactly
    atomicAdd(&cnt[dst[i]], 1);
}

__global__ void dinv_k(const int* __restrict__ cnt, float* __restrict__ dinv) {
    int i = blockIdx.x * blockDim.x + threadIdx.x;
    if (i < NN) dinv[i] = rsqrtf((float)cnt[i] + 1.0f);   // +1 self-loop
}

// ---------- CSR build: two-level exclusive scan + cursor fill ----------
__global__ void blocksum_k(const int* __restrict__ cnt, int* __restrict__ bsum) {
    __shared__ int s[256];
    int i = blockIdx.x * 256 + threadIdx.x;
    s[threadIdx.x] = (i < NN) ? cnt[i] : 0;
    __syncthreads();
    for (int off = 128; off > 0; off >>= 1) {
        if (threadIdx.x < off) s[threadIdx.x] += s[threadIdx.x + off];
        __syncthreads();
    }
    if (threadIdx.x == 0) bsum[blockIdx.x] = s[0];
}

__global__ void scan_bsum_k(const int* __restrict__ bsum, int* __restrict__ boff) {
    __shared__ int s[512];                           // 1 block of 512 covers NBLK=391
    int t = threadIdx.x;
    int v = (t < NBLK) ? bsum[t] : 0;
    s[t] = v;
    __syncthreads();
    for (int off = 1; off < 512; off <<= 1) {
        int tmp = (t >= off) ? s[t - off] : 0;
        __syncthreads();
        s[t] += tmp;
        __syncthreads();
    }
    if (t < NBLK) boff[t] = s[t] - v;                // exclusive
}

__global__ void scan_block_k(const int* __restrict__ cnt, const int* __restrict__ boff,
                             int* __restrict__ row_ptr, int* __restrict__ cursor) {
    __shared__ int s[256];
    int t = threadIdx.x, i = blockIdx.x * 256 + t;
    int v = (i < NN) ? cnt[i] : 0;
    s[t] = v;
    __syncthreads();
    for (int off = 1; off < 256; off <<= 1) {
        int tmp = (t >= off) ? s[t - off] : 0;
        __syncthreads();
        s[t] += tmp;
        __syncthreads();
    }
    if (i < NN) {
        int e = boff[blockIdx.x] + s[t] - v;         // global exclusive
        row_ptr[i] = e;
        cursor[i] = e;
    }
    if (i == NN - 1) row_ptr[NN] = NE;
}

__global__ void fill_k(const int* __restrict__ src, const int* __restrict__ dst,
                       int* __restrict__ cursor, int* __restrict__ csr_src) {
    int e = blockIdx.x * 256 + threadIdx.x;          // grid = NE exactly
    int d = dst[e];
    int pos = atomicAdd(&cursor[d], 1);
    csr_src[pos] = src[e];
}

// ---------- CSR gather: one wave per dst node, no atomics ----------
// v2: two edges in flight per wave (lane>>5 selects edge), float4 loads.
// Halves the serial per-edge dependency chain and the shfl count per edge.
template <typename ST>
__global__ __launch_bounds__(256) void gather_k(const int* __restrict__ row_ptr,
                                                const int* __restrict__ csr_src,
                                                const float* __restrict__ dinv,
                                                const ST* __restrict__ h,
                                                float* __restrict__ agg) {
    int w = blockIdx.x * 4 + (threadIdx.x >> 6);     // node id; grid = NN/4 exactly
    if (w >= NN) return;
    int lane = threadIdx.x & 63;
    int eh = lane >> 5;                              // which of 2 concurrent edges
    int l  = lane & 31;                              // column group: cols l*4 .. l*4+3
    int beg = row_ptr[w], end = row_ptr[w + 1];
    float dd = dinv[w];
    float ax = 0.f, ay = 0.f, az = 0.f, aw = 0.f;
    for (int base = beg; base < end; base += 64) {
        int k = end - base;
        if (k > 64) k = 64;
        int s = 0;
        float ns = 0.f;
        if (lane < k) { s = csr_src[base + lane]; ns = dinv[s]; }
        for (int j = 0; j < k; j += 2) {
            int   sj = __shfl(s,  j + eh);
            float nj = __shfl(ns, j + eh);
            float4 hv = ld4(&h[(size_t)sj * DIM + l * 4]);  // 16B/lane, 512B/edge
            ax = fmaf(hv.x, nj, ax);
            ay = fmaf(hv.y, nj, ay);
            az = fmaf(hv.z, nj, az);
            aw = fmaf(hv.w, nj, aw);
        }
    }
    // combine the two half-wave partials (lane ^ 32)
    ax += __shfl_xor(ax, 32);
    ay += __shfl_xor(ay, 32);
    az += __shfl_xor(az, 32);
    aw += __shfl_xor(aw, 32);
    if (eh == 0) {
        reinterpret_cast<float4*>(&agg[(size_t)w * DIM])[l] =
            make_float4(ax * dd, ay * dd, az * dd, aw * dd);
    }
}

// ---------- atomic scatter (fallback for tiny ws) ----------
template <typename ST>
__global__ void scatter_k(const int* __restrict__ src, const int* __restrict__ dst,
                          const float* __restrict__ dinv, const ST* __restrict__ S,
                          float* __restrict__ agg) {
    int i = blockIdx.x * blockDim.x + threadIdx.x;   // grid = NE*32 exactly
    int e = i >> 5;
    int p = (i & 31) * 4;
    int s = src[e], d = dst[e];
    float nrm = dinv[s] * dinv[d];
    float4 hv = ld4(&S[(size_t)s * DIM + p]);
    float* ap = &agg[(size_t)d * DIM + p];
    atomicAdd(ap + 0, hv.x * nrm);
    atomicAdd(ap + 1, hv.y * nrm);
    atomicAdd(ap + 2, hv.z * nrm);
    atomicAdd(ap + 3, hv.w * nrm);
}

// ---------- fused GEMM: out = act((agg + S*dinv^2) @ W + b) ----------
// v2: register-blocked. 32 rows x 128 cols per 256-thread block; each thread
// computes a 4x4 register tile. W is NOT staged in LDS: it's 64 KB read
// identically by every block -> L1/L2-resident global float4 loads. Only x
// (32x128, 16 KB) goes to LDS -> up to 8 blocks/CU instead of 2.
// Per k: 1 global_load_dwordx4 (W) + 4 LDS broadcast reads + 16 FMAs.
// agg/S/out may alias row-wise (in-place safe: block reads only its own rows
// before __syncthreads, writes them at the end).
template <typename ST, typename OT, bool RELU>
__global__ __launch_bounds__(256) void gemm_fused_k(const float* agg, const ST* S,
                                                    const float* __restrict__ dinv,
                                                    const float* __restrict__ W,
                                                    const float* __restrict__ bias,
                                                    OT* out) {
    __shared__ float xs[32][DIM];                    // 16 KB
    const int t = threadIdx.x;
    const int r0 = blockIdx.x * 32;                  // grid = NN/32 exactly

    // stage 32 rows of x = agg + S*dinv^2 into LDS (float4, fully coalesced)
#pragma unroll
    for (int i = 0; i < 4; ++i) {
        int idx = t + i * 256;                       // float4 slot 0..1023
        int rr = idx >> 5;                           // 32 float4 per row
        int c4 = (idx & 31) * 4;
        int r = r0 + rr;
        float di = dinv[r];
        float d2 = di * di;
        size_t off = (size_t)r * DIM + c4;
        float4 a = *reinterpret_cast<const float4*>(&agg[off]);
        float4 s = ld4(&S[off]);
        xs[rr][c4 + 0] = fmaf(s.x, d2, a.x);
        xs[rr][c4 + 1] = fmaf(s.y, d2, a.y);
        xs[rr][c4 + 2] = fmaf(s.z, d2, a.z);
        xs[rr][c4 + 3] = fmaf(s.w, d2, a.w);
    }
    __syncthreads();

    const int cw = t & 31;                           // col group: cols cw*4..cw*4+3
    const int rb = (t >> 5) * 4;                     // rows rb..rb+3 (rb in 0..28)
    const float4* __restrict__ Wv = reinterpret_cast<const float4*>(W);

    float4 acc0 = make_float4(0.f, 0.f, 0.f, 0.f);
    float4 acc1 = acc0, acc2 = acc0, acc3 = acc0;

#pragma unroll 4
    for (int k = 0; k < DIM; ++k) {
        float4 w = Wv[k * 32 + cw];                  // W[k][cw*4..cw*4+3], L1-hot
        float x0 = xs[rb + 0][k];
        float x1 = xs[rb + 1][k];
        float x2 = xs[rb + 2][k];
        float x3 = xs[rb + 3][k];
        acc0.x = fmaf(x0, w.x, acc0.x);
        acc0.y = fmaf(x0, w.y, acc0.y);
        acc0.z = fmaf(x0, w.z, acc0.z);
        acc0.w = fmaf(x0, w.w, acc0.w);
        acc1.x = fmaf(x1, w.x, acc1.x);
        acc1.y = fmaf(x1, w.y, acc1.y);
        acc1.z = fmaf(x1, w.z, acc1.z);
        acc1.w = fmaf(x1, w.w, acc1.w);
        acc2.x = fmaf(x2, w.x, acc2.x);
        acc2.y = fmaf(x2, w.y, acc2.y);
        acc2.z = fmaf(x2, w.z, acc2.z);
        acc2.w = fmaf(x2, w.w, acc2.w);
        acc3.x = fmaf(x3, w.x, acc3.x);
        acc3.y = fmaf(x3, w.y, acc3.y);
        acc3.z = fmaf(x3, w.z, acc3.z);
        acc3.w = fmaf(x3, w.w, acc3.w);
    }

    float4 b4 = *reinterpret_cast<const float4*>(&bias[cw * 4]);
    auto fin = [&](float4 a) {
        a.x += b4.x; a.y += b4.y; a.z += b4.z; a.w += b4.w;
        if (RELU) {
            a.x = fmaxf(a.x, 0.f); a.y = fmaxf(a.y, 0.f);
            a.z = fmaxf(a.z, 0.f); a.w = fmaxf(a.w, 0.f);
        }
        return a;
    };
    size_t o = (size_t)(r0 + rb) * DIM + cw * 4;
    st4(&out[o], fin(acc0));
    st4(&out[o + DIM], fin(acc1));
    st4(&out[o + 2 * DIM], fin(acc2));
    st4(&out[o + 3 * DIM], fin(acc3));
}

// ---------- tier-3 utilities ----------
__global__ void compress_k(const float* __restrict__ src, bf16* __restrict__ dst) {
    int i = blockIdx.x * blockDim.x + threadIdx.x;   // grid = NB/256 exactly
    dst[i] = __float2bfloat16(src[i]);
}
__global__ void decomp_k(float* __restrict__ dst, const bf16* __restrict__ src, int n) {
    int i = blockIdx.x * blockDim.x + threadIdx.x;
    if (i < n) dst[i] = __bfloat162float(src[i]);
}

// ---------- driver ----------
// ws layout (CSR mode, needs >= 9 MiB):
//   cnt     @ 0        (400 KB, int)
//   dinv    @ 512 KiB  (400 KB)
//   row_ptr @ 1 MiB    (400 KB)
//   cursor  @ 1.5 MiB  (400 KB)
//   bsum    @ 2 MiB    (1.6 KB), boff @ 2 MiB + 4 KB
//   csr_src @ 2.25 MiB (6.4 MB)
//   big     @ 9 MiB    (graph-1 H tiers)
// Fallback mode (ws < 9 MiB): cnt/dinv as above, big @ 1 MiB, atomic scatter.
extern "C" void kernel_launch(void* const* d_in, const int* in_sizes, int n_in,
                              void* d_out, int out_size, void* d_ws, size_t ws_size,
                              hipStream_t stream) {
    const float* W0 = (const float*)d_in[4];
    const float* b0 = (const float*)d_in[5];
    const float* W1 = (const float*)d_in[6];
    const float* b1 = (const float*)d_in[7];

    char* ws = (char*)d_ws;
    int*   cnt  = (int*)ws;
    float* dinv = (float*)(ws + (512u << 10));
    int* row_ptr = (int*)(ws + (1u << 20));
    int* cursor  = (int*)(ws + (3u << 19));
    int* bsum    = (int*)(ws + (2u << 20));
    int* boff    = (int*)(ws + (2u << 20) + 4096);
    int* csr_src = (int*)(ws + (9u << 18));          // 2.25 MiB

    const bool csr_ok = ws_size >= (9u << 20);
    char* big = csr_ok ? ws + (9u << 20) : ws + (1u << 20);
    size_t big_avail = ws_size - (csr_ok ? (9u << 20) : (1u << 20));

    const size_t NB = (size_t)NN * DIM;
    float* slot0 = (float*)d_out;
    float* slot1 = slot0 + NB;

    const int SG = (NE * 32) / 256;
    const int GG = NN / 32;                          // 3125, register-blocked GEMM
    const int CG = NE / 256;

    auto build = [&](const int* srcp, const int* dstp) {
        hipMemsetAsync(cnt, 0, NN * sizeof(int), stream);
        count_deg_k<<<CG, 256, 0, stream>>>(dstp, cnt);
        dinv_k<<<(NN + 255) / 256, 256, 0, stream>>>(cnt, dinv);
        if (!csr_ok) return;
        blocksum_k<<<NBLK, 256, 0, stream>>>(cnt, bsum);
        scan_bsum_k<<<1, 512, 0, stream>>>(bsum, boff);
        scan_block_k<<<NBLK, 256, 0, stream>>>(cnt, boff, row_ptr, cursor);
        fill_k<<<CG, 256, 0, stream>>>(srcp, dstp, cursor, csr_src);
    };
    auto agg_f = [&](const int* srcp, const int* dstp, const float* h, float* agg) {
        if (csr_ok) {
            gather_k<float><<<NN / 4, 256, 0, stream>>>(row_ptr, csr_src, dinv, h, agg);
        } else {
            hipMemsetAsync(agg, 0, NB * sizeof(float), stream);
            scatter_k<float><<<SG, 256, 0, stream>>>(srcp, dstp, dinv, h, agg);
        }
    };
    auto agg_b = [&](const int* srcp, const int* dstp, const bf16* h, float* agg) {
        if (csr_ok) {
            gather_k<bf16><<<NN / 4, 256, 0, stream>>>(row_ptr, csr_src, dinv, h, agg);
        } else {
            hipMemsetAsync(agg, 0, NB * sizeof(float), stream);
            scatter_k<bf16><<<SG, 256, 0, stream>>>(srcp, dstp, dinv, h, agg);
        }
    };

    // ================= graph 0 (h in slot1, result in slot0) =================
    {
        const float* x  = (const float*)d_in[0];
        const int*   ei = (const int*)d_in[1];
        build(ei, ei + NE);
        agg_f(ei, ei + NE, x, slot1);
        gemm_fused_k<float, float, true><<<GG, 256, 0, stream>>>(slot1, x, dinv, W0, b0, slot1);
        agg_f(ei, ei + NE, slot1, slot0);
        gemm_fused_k<float, float, false><<<GG, 256, 0, stream>>>(slot0, slot1, dinv, W1, b1, slot0);
    }

    // ================= graph 1 =================
    {
        const float* x  = (const float*)d_in[2];
        const int*   ei = (const int*)d_in[3];
        build(ei, ei + NE);

        if (big_avail >= NB * sizeof(float)) {
            // tier 1: fp32 H in ws
            float* H = (float*)big;
            agg_f(ei, ei + NE, x, H);
            gemm_fused_k<float, float, true><<<GG, 256, 0, stream>>>(H, x, dinv, W0, b0, H);
            agg_f(ei, ei + NE, H, slot1);
            gemm_fused_k<float, float, false><<<GG, 256, 0, stream>>>(slot1, H, dinv, W1, b1, slot1);
        } else if (big_avail >= NB * sizeof(bf16)) {
            // tier 2: bf16 H in ws
            bf16* H = (bf16*)big;
            agg_f(ei, ei + NE, x, slot1);
            gemm_fused_k<float, bf16, true><<<GG, 256, 0, stream>>>(slot1, x, dinv, W0, b0, H);
            agg_b(ei, ei + NE, H, slot1);
            gemm_fused_k<bf16, float, false><<<GG, 256, 0, stream>>>(slot1, H, dinv, W1, b1, slot1);
        } else {
            // tier 3: stash g0 as bf16 in slot1 low half, h1 as bf16 in slot1 high half
            bf16* g0b = (bf16*)slot1;
            bf16* h1b = (bf16*)((char*)slot1 + NB * sizeof(bf16));
            compress_k<<<(int)(NB / 256), 256, 0, stream>>>(slot0, g0b);
            agg_f(ei, ei + NE, x, slot0);
            gemm_fused_k<float, bf16, true><<<GG, 256, 0, stream>>>(slot0, x, dinv, W0, b0, h1b);
            agg_b(ei, ei + NE, h1b, slot0);
            gemm_fused_k<bf16, float, false><<<GG, 256, 0, stream>>>(slot0, h1b, dinv, W1, b1, slot0);
            // swap: slot0 (g1) -> slot1, decompress g0b -> slot0, descending chunks.
            float* stage;
            size_t C;
            if (csr_ok) { stage = (float*)csr_src; C = 1600000; }   // CSR dead now
            else {
                stage = (float*)big;
                C = (big_avail / sizeof(float)) & ~(size_t)255;
                if (C < 256) C = 256;
            }
            size_t a = NB;
            while (a > 0) {
                size_t len = (a >= C) ? C : a;
                a -= len;
                hipMemcpyAsync(stage, slot0 + a, len * sizeof(float),
                               hipMemcpyDeviceToDevice, stream);
                decomp_k<<<(int)((len + 255) / 256), 256, 0, stream>>>(slot0 + a, g0b + a, (int)len);
                hipMemcpyAsync(slot1 + a, stage, len * sizeof(float),
                               hipMemcpyDeviceToDevice, stream);
            }
        }
    }
}

// Round 4
// 1118.122 us; speedup vs baseline: 1.4019x; 1.1253x over previous
//
#include <hip/hip_runtime.h>
#include <hip/hip_bf16.h>

#define NN 100000
#define NE 1600000
#define DIM 128
#define NBLK ((NN + 255) / 256)   // 391

// XCD-sliced CSR build: 8 dst-slices of 12500 nodes, 128 edge-chunks of 12500
#define NSLICE 8
#define SLICE_N 12500             // NN / 8
#define NCHUNK 128
#define CHUNK_E 12500             // NE / 128

using bf16 = __hip_bfloat16;
using bf162 = __hip_bfloat162;

// ---------- dtype helpers ----------
__device__ __forceinline__ float to_f(const float v) { return v; }
__device__ __forceinline__ float to_f(const bf16 v) { return __bfloat162float(v); }

__device__ __forceinline__ float4 ld4(const float* p) {
    return *reinterpret_cast<const float4*>(p);
}
__device__ __forceinline__ float4 ld4(const bf16* p) {
    const bf162* q = reinterpret_cast<const bf162*>(p);
    float2 a = __bfloat1622float2(q[0]);
    float2 b = __bfloat1622float2(q[1]);
    return make_float4(a.x, a.y, b.x, b.y);
}
__device__ __forceinline__ void st1(float* p, float v) { *p = v; }
__device__ __forceinline__ void st1(bf16* p, float v) { *p = __float2bfloat16(v); }
__device__ __forceinline__ void st4(float* p, float4 v) {
    *reinterpret_cast<float4*>(p) = v;
}
__device__ __forceinline__ void st4(bf16* p, float4 v) {
    bf162* q = reinterpret_cast<bf162*>(p);
    q[0] = __float22bfloat162_rn(make_float2(v.x, v.y));
    q[1] = __float22bfloat162_rn(make_float2(v.z, v.w));
}

// ---------- degree / normalization ----------
// XCD-sliced: blockIdx&7 selects a dst-slice (lands on one XCD under
// round-robin dispatch) so the atomic working set per XCD is 50 KB, L2-local.
// Edge list is re-read 8x but served by the shared 256 MB L3.
__global__ __launch_bounds__(256) void count_deg_k(const int* __restrict__ dst,
                                                   int* __restrict__ cnt) {
    const int s = blockIdx.x & 7;
    const int c = blockIdx.x >> 3;                   // grid = NCHUNK*8
    const int lo = s * SLICE_N;
    const int beg = c * CHUNK_E, end = beg + CHUNK_E;
    for (int e = beg + threadIdx.x; e < end; e += 256) {
        int d = dst[e];
        if ((unsigned)(d - lo) < (unsigned)SLICE_N) atomicAdd(&cnt[d], 1);
    }
}

__global__ void dinv_k(const int* __restrict__ cnt, float* __restrict__ dinv) {
    int i = blockIdx.x * blockDim.x + threadIdx.x;
    if (i < NN) dinv[i] = rsqrtf((float)cnt[i] + 1.0f);   // +1 self-loop
}

// ---------- CSR build: two-level exclusive scan + cursor fill ----------
__global__ void blocksum_k(const int* __restrict__ cnt, int* __restrict__ bsum) {
    __shared__ int s[256];
    int i = blockIdx.x * 256 + threadIdx.x;
    s[threadIdx.x] = (i < NN) ? cnt[i] : 0;
    __syncthreads();
    for (int off = 128; off > 0; off >>= 1) {
        if (threadIdx.x < off) s[threadIdx.x] += s[threadIdx.x + off];
        __syncthreads();
    }
    if (threadIdx.x == 0) bsum[blockIdx.x] = s[0];
}

__global__ void scan_bsum_k(const int* __restrict__ bsum, int* __restrict__ boff) {
    __shared__ int s[512];                           // 1 block of 512 covers NBLK=391
    int t = threadIdx.x;
    int v = (t < NBLK) ? bsum[t] : 0;
    s[t] = v;
    __syncthreads();
    for (int off = 1; off < 512; off <<= 1) {
        int tmp = (t >= off) ? s[t - off] : 0;
        __syncthreads();
        s[t] += tmp;
        __syncthreads();
    }
    if (t < NBLK) boff[t] = s[t] - v;                // exclusive
}

__global__ void scan_block_k(const int* __restrict__ cnt, const int* __restrict__ boff,
                             int* __restrict__ row_ptr, int* __restrict__ cursor) {
    __shared__ int s[256];
    int t = threadIdx.x, i = blockIdx.x * 256 + t;
    int v = (i < NN) ? cnt[i] : 0;
    s[t] = v;
    __syncthreads();
    for (int off = 1; off < 256; off <<= 1) {
        int tmp = (t >= off) ? s[t - off] : 0;
        __syncthreads();
        s[t] += tmp;
        __syncthreads();
    }
    if (i < NN) {
        int e = boff[blockIdx.x] + s[t] - v;         // global exclusive
        row_ptr[i] = e;
        cursor[i] = e;
    }
    if (i == NN - 1) row_ptr[NN] = NE;
}

// XCD-sliced cursor fill: same slicing as count_deg_k. Each slice's csr_src
// output region is ~0.8 MB -> fits one XCD's L2, lines filled by one XCD only
// -> write amplification ~1 (was 16x: 105 MB WRITE_SIZE for 6.8 MB useful).
__global__ __launch_bounds__(256) void fill_k(const int* __restrict__ src,
                                              const int* __restrict__ dst,
                                              int* __restrict__ cursor,
                                              int* __restrict__ csr_src) {
    const int s = blockIdx.x & 7;
    const int c = blockIdx.x >> 3;                   // grid = NCHUNK*8
    const int lo = s * SLICE_N;
    const int beg = c * CHUNK_E, end = beg + CHUNK_E;
    for (int e = beg + threadIdx.x; e < end; e += 256) {
        int d = dst[e];
        if ((unsigned)(d - lo) < (unsigned)SLICE_N) {
            int pos = atomicAdd(&cursor[d], 1);
            csr_src[pos] = src[e];
        }
    }
}

// ---------- CSR gather: one wave per dst node, no atomics ----------
// v2: two edges in flight per wave (lane>>5 selects edge), float4 loads.
template <typename ST>
__global__ __launch_bounds__(256) void gather_k(const int* __restrict__ row_ptr,
                                                const int* __restrict__ csr_src,
                                                const float* __restrict__ dinv,
                                                const ST* __restrict__ h,
                                                float* __restrict__ agg) {
    int w = blockIdx.x * 4 + (threadIdx.x >> 6);     // node id; grid = NN/4 exactly
    if (w >= NN) return;
    int lane = threadIdx.x & 63;
    int eh = lane >> 5;                              // which of 2 concurrent edges
    int l  = lane & 31;                              // column group: cols l*4 .. l*4+3
    int beg = row_ptr[w], end = row_ptr[w + 1];
    float dd = dinv[w];
    float ax = 0.f, ay = 0.f, az = 0.f, aw = 0.f;
    for (int base = beg; base < end; base += 64) {
        int k = end - base;
        if (k > 64) k = 64;
        int s = 0;
        float ns = 0.f;
        if (lane < k) { s = csr_src[base + lane]; ns = dinv[s]; }
        for (int j = 0; j < k; j += 2) {
            int   sj = __shfl(s,  j + eh);
            float nj = __shfl(ns, j + eh);
            float4 hv = ld4(&h[(size_t)sj * DIM + l * 4]);
            ax = fmaf(hv.x, nj, ax);
            ay = fmaf(hv.y, nj, ay);
            az = fmaf(hv.z, nj, az);
            aw = fmaf(hv.w, nj, aw);
        }
    }
    // combine the two half-wave partials (lane ^ 32)
    ax += __shfl_xor(ax, 32);
    ay += __shfl_xor(ay, 32);
    az += __shfl_xor(az, 32);
    aw += __shfl_xor(aw, 32);
    if (eh == 0) {
        reinterpret_cast<float4*>(&agg[(size_t)w * DIM])[l] =
            make_float4(ax * dd, ay * dd, az * dd, aw * dd);
    }
}

// ---------- atomic scatter (fallback for tiny ws) ----------
template <typename ST>
__global__ void scatter_k(const int* __restrict__ src, const int* __restrict__ dst,
                          const float* __restrict__ dinv, const ST* __restrict__ S,
                          float* __restrict__ agg) {
    int i = blockIdx.x * blockDim.x + threadIdx.x;   // grid = NE*32 exactly
    int e = i >> 5;
    int p = (i & 31) * 4;
    int s = src[e], d = dst[e];
    float nrm = dinv[s] * dinv[d];
    float4 hv = ld4(&S[(size_t)s * DIM + p]);
    float* ap = &agg[(size_t)d * DIM + p];
    atomicAdd(ap + 0, hv.x * nrm);
    atomicAdd(ap + 1, hv.y * nrm);
    atomicAdd(ap + 2, hv.z * nrm);
    atomicAdd(ap + 3, hv.w * nrm);
}

// ---------- fused GEMM: out = act((agg + S*dinv^2) @ W + b) ----------
// Register-blocked: 32 rows x 128 cols per 256-thread block, 4x4 tile/thread.
// W read from global (L1/L2-hot), only x staged in LDS (16 KB).
// agg/out may alias row-wise when same dtype/layout (in-place safe).
template <typename ST, typename OT, bool RELU>
__global__ __launch_bounds__(256) void gemm_fused_k(const float* agg, const ST* S,
                                                    const float* __restrict__ dinv,
                                                    const float* __restrict__ W,
                                                    const float* __restrict__ bias,
                                                    OT* out) {
    __shared__ float xs[32][DIM];                    // 16 KB
    const int t = threadIdx.x;
    const int r0 = blockIdx.x * 32;                  // grid = NN/32 exactly

#pragma unroll
    for (int i = 0; i < 4; ++i) {
        int idx = t + i * 256;                       // float4 slot 0..1023
        int rr = idx >> 5;                           // 32 float4 per row
        int c4 = (idx & 31) * 4;
        int r = r0 + rr;
        float di = dinv[r];
        float d2 = di * di;
        size_t off = (size_t)r * DIM + c4;
        float4 a = *reinterpret_cast<const float4*>(&agg[off]);
        float4 s = ld4(&S[off]);
        xs[rr][c4 + 0] = fmaf(s.x, d2, a.x);
        xs[rr][c4 + 1] = fmaf(s.y, d2, a.y);
        xs[rr][c4 + 2] = fmaf(s.z, d2, a.z);
        xs[rr][c4 + 3] = fmaf(s.w, d2, a.w);
    }
    __syncthreads();

    const int cw = t & 31;                           // col group: cols cw*4..cw*4+3
    const int rb = (t >> 5) * 4;                     // rows rb..rb+3
    const float4* __restrict__ Wv = reinterpret_cast<const float4*>(W);

    float4 acc0 = make_float4(0.f, 0.f, 0.f, 0.f);
    float4 acc1 = acc0, acc2 = acc0, acc3 = acc0;

#pragma unroll 4
    for (int k = 0; k < DIM; ++k) {
        float4 w = Wv[k * 32 + cw];                  // W[k][cw*4..cw*4+3], L1-hot
        float x0 = xs[rb + 0][k];
        float x1 = xs[rb + 1][k];
        float x2 = xs[rb + 2][k];
        float x3 = xs[rb + 3][k];
        acc0.x = fmaf(x0, w.x, acc0.x);
        acc0.y = fmaf(x0, w.y, acc0.y);
        acc0.z = fmaf(x0, w.z, acc0.z);
        acc0.w = fmaf(x0, w.w, acc0.w);
        acc1.x = fmaf(x1, w.x, acc1.x);
        acc1.y = fmaf(x1, w.y, acc1.y);
        acc1.z = fmaf(x1, w.z, acc1.z);
        acc1.w = fmaf(x1, w.w, acc1.w);
        acc2.x = fmaf(x2, w.x, acc2.x);
        acc2.y = fmaf(x2, w.y, acc2.y);
        acc2.z = fmaf(x2, w.z, acc2.z);
        acc2.w = fmaf(x2, w.w, acc2.w);
        acc3.x = fmaf(x3, w.x, acc3.x);
        acc3.y = fmaf(x3, w.y, acc3.y);
        acc3.z = fmaf(x3, w.z, acc3.z);
        acc3.w = fmaf(x3, w.w, acc3.w);
    }

    float4 b4 = *reinterpret_cast<const float4*>(&bias[cw * 4]);
    auto fin = [&](float4 a) {
        a.x += b4.x; a.y += b4.y; a.z += b4.z; a.w += b4.w;
        if (RELU) {
            a.x = fmaxf(a.x, 0.f); a.y = fmaxf(a.y, 0.f);
            a.z = fmaxf(a.z, 0.f); a.w = fmaxf(a.w, 0.f);
        }
        return a;
    };
    size_t o = (size_t)(r0 + rb) * DIM + cw * 4;
    st4(&out[o], fin(acc0));
    st4(&out[o + DIM], fin(acc1));
    st4(&out[o + 2 * DIM], fin(acc2));
    st4(&out[o + 3 * DIM], fin(acc3));
}

// ---------- tier-3 utilities ----------
__global__ void compress_k(const float* __restrict__ src, bf16* __restrict__ dst) {
    int i = blockIdx.x * blockDim.x + threadIdx.x;   // grid = NB/256 exactly
    dst[i] = __float2bfloat16(src[i]);
}
__global__ void decomp_k(float* __restrict__ dst, const bf16* __restrict__ src, int n) {
    int i = blockIdx.x * blockDim.x + threadIdx.x;
    if (i < n) dst[i] = __bfloat162float(src[i]);
}

// ---------- driver ----------
// ws layout (CSR mode, needs >= 9 MiB):
//   cnt @0 (400KB) | dinv @512K | row_ptr @1M | cursor @1.5M | bsum/boff @2M
//   csr_src @2.25M (6.4MB) | big @9M (graph-1 bf16 H tier)
// Fallback (ws < 9 MiB): atomic scatter, big @1M.
extern "C" void kernel_launch(void* const* d_in, const int* in_sizes, int n_in,
                              void* d_out, int out_size, void* d_ws, size_t ws_size,
                              hipStream_t stream) {
    const float* W0 = (const float*)d_in[4];
    const float* b0 = (const float*)d_in[5];
    const float* W1 = (const float*)d_in[6];
    const float* b1 = (const float*)d_in[7];

    char* ws = (char*)d_ws;
    int*   cnt  = (int*)ws;
    float* dinv = (float*)(ws + (512u << 10));
    int* row_ptr = (int*)(ws + (1u << 20));
    int* cursor  = (int*)(ws + (3u << 19));
    int* bsum    = (int*)(ws + (2u << 20));
    int* boff    = (int*)(ws + (2u << 20) + 4096);
    int* csr_src = (int*)(ws + (9u << 18));          // 2.25 MiB

    const bool csr_ok = ws_size >= (9u << 20);
    char* big = csr_ok ? ws + (9u << 20) : ws + (1u << 20);
    size_t big_avail = ws_size - (csr_ok ? (9u << 20) : (1u << 20));

    const size_t NB = (size_t)NN * DIM;
    float* slot0 = (float*)d_out;
    float* slot1 = slot0 + NB;

    const int SG = (NE * 32) / 256;
    const int GG = NN / 32;                          // 3125, register-blocked GEMM
    const int BG = NCHUNK * NSLICE;                  // 1024, sliced build kernels

    auto build = [&](const int* srcp, const int* dstp) {
        hipMemsetAsync(cnt, 0, NN * sizeof(int), stream);
        count_deg_k<<<BG, 256, 0, stream>>>(dstp, cnt);
        dinv_k<<<(NN + 255) / 256, 256, 0, stream>>>(cnt, dinv);
        if (!csr_ok) return;
        blocksum_k<<<NBLK, 256, 0, stream>>>(cnt, bsum);
        scan_bsum_k<<<1, 512, 0, stream>>>(bsum, boff);
        scan_block_k<<<NBLK, 256, 0, stream>>>(cnt, boff, row_ptr, cursor);
        fill_k<<<BG, 256, 0, stream>>>(srcp, dstp, cursor, csr_src);
    };
    auto agg_f = [&](const int* srcp, const int* dstp, const float* h, float* agg) {
        if (csr_ok) {
            gather_k<float><<<NN / 4, 256, 0, stream>>>(row_ptr, csr_src, dinv, h, agg);
        } else {
            hipMemsetAsync(agg, 0, NB * sizeof(float), stream);
            scatter_k<float><<<SG, 256, 0, stream>>>(srcp, dstp, dinv, h, agg);
        }
    };
    auto agg_b = [&](const int* srcp, const int* dstp, const bf16* h, float* agg) {
        if (csr_ok) {
            gather_k<bf16><<<NN / 4, 256, 0, stream>>>(row_ptr, csr_src, dinv, h, agg);
        } else {
            hipMemsetAsync(agg, 0, NB * sizeof(float), stream);
            scatter_k<bf16><<<SG, 256, 0, stream>>>(srcp, dstp, dinv, h, agg);
        }
    };

    // ===== graph 0: bf16 h1 in slot1 low half, everything else in slot0 =====
    // agg1 -> slot0 ; h1(bf16) -> slot1.lo ; agg2 -> slot0 (agg1 dead) ;
    // g0 = GEMM1(slot0, h1b) -> slot0 in-place (row-safe, same dtype/layout).
    {
        const float* x  = (const float*)d_in[0];
        const int*   ei = (const int*)d_in[1];
        bf16* h1b = (bf16*)slot1;                    // 25.6 MB
        build(ei, ei + NE);
        agg_f(ei, ei + NE, x, slot0);
        gemm_fused_k<float, bf16, true><<<GG, 256, 0, stream>>>(slot0, x, dinv, W0, b0, h1b);
        agg_b(ei, ei + NE, h1b, slot0);
        gemm_fused_k<bf16, float, false><<<GG, 256, 0, stream>>>(slot0, h1b, dinv, W1, b1, slot0);
    }

    // ================= graph 1 =================
    {
        const float* x  = (const float*)d_in[2];
        const int*   ei = (const int*)d_in[3];
        build(ei, ei + NE);

        if (big_avail >= NB * sizeof(bf16)) {
            // bf16 H in ws (tiers 1+2 unified: bf16 numerics are harness-proven)
            bf16* H = (bf16*)big;
            agg_f(ei, ei + NE, x, slot1);
            gemm_fused_k<float, bf16, true><<<GG, 256, 0, stream>>>(slot1, x, dinv, W0, b0, H);
            agg_b(ei, ei + NE, H, slot1);
            gemm_fused_k<bf16, float, false><<<GG, 256, 0, stream>>>(slot1, H, dinv, W1, b1, slot1);
        } else {
            // tier 3: stash g0 as bf16 in slot1 low half, h1 as bf16 in high half
            bf16* g0b = (bf16*)slot1;
            bf16* h1b = (bf16*)((char*)slot1 + NB * sizeof(bf16));
            compress_k<<<(int)(NB / 256), 256, 0, stream>>>(slot0, g0b);
            agg_f(ei, ei + NE, x, slot0);
            gemm_fused_k<float, bf16, true><<<GG, 256, 0, stream>>>(slot0, x, dinv, W0, b0, h1b);
            agg_b(ei, ei + NE, h1b, slot0);
            gemm_fused_k<bf16, float, false><<<GG, 256, 0, stream>>>(slot0, h1b, dinv, W1, b1, slot0);
            // swap: slot0 (g1) -> slot1, decompress g0b -> slot0, descending chunks.
            float* stage;
            size_t C;
            if (csr_ok) { stage = (float*)csr_src; C = 1600000; }   // CSR dead now
            else {
                stage = (float*)big;
                C = (big_avail / sizeof(float)) & ~(size_t)255;
                if (C < 256) C = 256;
            }
            size_t a = NB;
            while (a > 0) {
                size_t len = (a >= C) ? C : a;
                a -= len;
                hipMemcpyAsync(stage, slot0 + a, len * sizeof(float),
                               hipMemcpyDeviceToDevice, stream);
                decomp_k<<<(int)((len + 255) / 256), 256, 0, stream>>>(slot0 + a, g0b + a, (int)len);
                hipMemcpyAsync(slot1 + a, stage, len * sizeof(float),
                               hipMemcpyDeviceToDevice, stream);
            }
        }
    }
}

// Round 5
// 1071.651 us; speedup vs baseline: 1.4627x; 1.0434x over previous
//
#include <hip/hip_runtime.h>
#include <hip/hip_bf16.h>

#define NN 100000
#define NE 1600000
#define DIM 128
#define NBLK ((NN + 255) / 256)   // 391

// XCD-sliced CSR build: 8 dst-slices of 12500 nodes, 128 edge-chunks of 12500
#define NSLICE 8
#define SLICE_N 12500             // NN / 8
#define NCHUNK 128
#define CHUNK_E 12500             // NE / 128

using bf16 = __hip_bfloat16;
using bf162 = __hip_bfloat162;

// ---------- dtype helpers ----------
__device__ __forceinline__ float to_f(const float v) { return v; }
__device__ __forceinline__ float to_f(const bf16 v) { return __bfloat162float(v); }

__device__ __forceinline__ float4 ld4(const float* p) {
    return *reinterpret_cast<const float4*>(p);
}
__device__ __forceinline__ float4 ld4(const bf16* p) {
    const bf162* q = reinterpret_cast<const bf162*>(p);
    float2 a = __bfloat1622float2(q[0]);
    float2 b = __bfloat1622float2(q[1]);
    return make_float4(a.x, a.y, b.x, b.y);
}
__device__ __forceinline__ void st1(float* p, float v) { *p = v; }
__device__ __forceinline__ void st1(bf16* p, float v) { *p = __float2bfloat16(v); }
__device__ __forceinline__ void st4(float* p, float4 v) {
    *reinterpret_cast<float4*>(p) = v;
}
__device__ __forceinline__ void st4(bf16* p, float4 v) {
    bf162* q = reinterpret_cast<bf162*>(p);
    q[0] = __float22bfloat162_rn(make_float2(v.x, v.y));
    q[1] = __float22bfloat162_rn(make_float2(v.z, v.w));
}

// ---------- degree / normalization ----------
// XCD-sliced: blockIdx&7 selects a dst-slice (lands on one XCD under
// round-robin dispatch) -> atomic working set per XCD is L2-local.
__global__ __launch_bounds__(256) void count_deg_k(const int* __restrict__ dst,
                                                   int* __restrict__ cnt) {
    const int s = blockIdx.x & 7;
    const int c = blockIdx.x >> 3;                   // grid = NCHUNK*8
    const int lo = s * SLICE_N;
    const int beg = c * CHUNK_E, end = beg + CHUNK_E;
    for (int e = beg + threadIdx.x; e < end; e += 256) {
        int d = dst[e];
        if ((unsigned)(d - lo) < (unsigned)SLICE_N) atomicAdd(&cnt[d], 1);
    }
}

__global__ void dinv_k(const int* __restrict__ cnt, float* __restrict__ dinv) {
    int i = blockIdx.x * blockDim.x + threadIdx.x;
    if (i < NN) dinv[i] = rsqrtf((float)cnt[i] + 1.0f);   // +1 self-loop
}

// ---------- CSR build: two-level exclusive scan + cursor fill ----------
__global__ void blocksum_k(const int* __restrict__ cnt, int* __restrict__ bsum) {
    __shared__ int s[256];
    int i = blockIdx.x * 256 + threadIdx.x;
    s[threadIdx.x] = (i < NN) ? cnt[i] : 0;
    __syncthreads();
    for (int off = 128; off > 0; off >>= 1) {
        if (threadIdx.x < off) s[threadIdx.x] += s[threadIdx.x + off];
        __syncthreads();
    }
    if (threadIdx.x == 0) bsum[blockIdx.x] = s[0];
}

__global__ void scan_bsum_k(const int* __restrict__ bsum, int* __restrict__ boff) {
    __shared__ int s[512];                           // 1 block of 512 covers NBLK=391
    int t = threadIdx.x;
    int v = (t < NBLK) ? bsum[t] : 0;
    s[t] = v;
    __syncthreads();
    for (int off = 1; off < 512; off <<= 1) {
        int tmp = (t >= off) ? s[t - off] : 0;
        __syncthreads();
        s[t] += tmp;
        __syncthreads();
    }
    if (t < NBLK) boff[t] = s[t] - v;                // exclusive
}

__global__ void scan_block_k(const int* __restrict__ cnt, const int* __restrict__ boff,
                             int* __restrict__ row_ptr, int* __restrict__ cursor) {
    __shared__ int s[256];
    int t = threadIdx.x, i = blockIdx.x * 256 + t;
    int v = (i < NN) ? cnt[i] : 0;
    s[t] = v;
    __syncthreads();
    for (int off = 1; off < 256; off <<= 1) {
        int tmp = (t >= off) ? s[t - off] : 0;
        __syncthreads();
        s[t] += tmp;
        __syncthreads();
    }
    if (i < NN) {
        int e = boff[blockIdx.x] + s[t] - v;         // global exclusive
        row_ptr[i] = e;
        cursor[i] = e;
    }
    if (i == NN - 1) row_ptr[NN] = NE;
}

// XCD-sliced cursor fill (same slicing as count_deg_k): per-slice csr_src
// region is ~0.8 MB -> one XCD's L2, write amplification ~1.
__global__ __launch_bounds__(256) void fill_k(const int* __restrict__ src,
                                              const int* __restrict__ dst,
                                              int* __restrict__ cursor,
                                              int* __restrict__ csr_src) {
    const int s = blockIdx.x & 7;
    const int c = blockIdx.x >> 3;                   // grid = NCHUNK*8
    const int lo = s * SLICE_N;
    const int beg = c * CHUNK_E, end = beg + CHUNK_E;
    for (int e = beg + threadIdx.x; e < end; e += 256) {
        int d = dst[e];
        if ((unsigned)(d - lo) < (unsigned)SLICE_N) {
            int pos = atomicAdd(&cursor[d], 1);
            csr_src[pos] = src[e];
        }
    }
}

// ---------- FUSED gather + GEMM ----------
// out[r] = act( (dd*sum_{s in N(r)} dinv[s]*h[s] + dd^2*h[r]) @ W + b )
// Block = 32 nodes (grid NN/32 = 3125). Phase 1: each of 4 waves gathers 8
// nodes (v2 scheme: 2 edges in flight via half-waves, float4 loads), adds the
// self-loop term, writes the row into LDS xs. Phase 2: register-blocked GEMM
// (4x4 tile/thread), W from global (L1/L2-hot). No global agg round-trip.
template <typename ST, typename OT, bool RELU>
__global__ __launch_bounds__(256) void fused_gg_k(const int* __restrict__ row_ptr,
                                                  const int* __restrict__ csr_src,
                                                  const float* __restrict__ dinv,
                                                  const ST* __restrict__ h,
                                                  const float* __restrict__ W,
                                                  const float* __restrict__ bias,
                                                  OT* __restrict__ out) {
    __shared__ float xs[32][DIM];                    // 16 KB
    const int t = threadIdx.x;
    const int r0 = blockIdx.x * 32;                  // grid = NN/32 exactly
    const int wv = t >> 6;                           // wave 0..3
    const int lane = t & 63;
    const int eh = lane >> 5;                        // which of 2 concurrent edges
    const int l = lane & 31;                         // col group: cols l*4..l*4+3

    // ---- phase 1: gather 8 nodes per wave ----
    for (int i = 0; i < 8; ++i) {
        const int nd = r0 + wv * 8 + i;
        const int beg = row_ptr[nd], end = row_ptr[nd + 1];
        const float dd = dinv[nd];
        float ax = 0.f, ay = 0.f, az = 0.f, aw = 0.f;
        for (int base = beg; base < end; base += 64) {
            int k = end - base;
            if (k > 64) k = 64;
            int s = 0;
            float ns = 0.f;
            if (lane < k) { s = csr_src[base + lane]; ns = dinv[s]; }
            for (int j = 0; j < k; j += 2) {
                int   sj = __shfl(s,  j + eh);
                float nj = __shfl(ns, j + eh);
                float4 hv = ld4(&h[(size_t)sj * DIM + l * 4]);
                ax = fmaf(hv.x, nj, ax);
                ay = fmaf(hv.y, nj, ay);
                az = fmaf(hv.z, nj, az);
                aw = fmaf(hv.w, nj, aw);
            }
        }
        ax += __shfl_xor(ax, 32);
        ay += __shfl_xor(ay, 32);
        az += __shfl_xor(az, 32);
        aw += __shfl_xor(aw, 32);
        if (eh == 0) {
            float4 sv = ld4(&h[(size_t)nd * DIM + l * 4]);   // self row, coalesced
            float d2 = dd * dd;
            xs[wv * 8 + i][l * 4 + 0] = fmaf(sv.x, d2, ax * dd);
            xs[wv * 8 + i][l * 4 + 1] = fmaf(sv.y, d2, ay * dd);
            xs[wv * 8 + i][l * 4 + 2] = fmaf(sv.z, d2, az * dd);
            xs[wv * 8 + i][l * 4 + 3] = fmaf(sv.w, d2, aw * dd);
        }
    }
    __syncthreads();

    // ---- phase 2: GEMM (register-blocked, 4x4 tile/thread) ----
    const int cw = t & 31;                           // cols cw*4..cw*4+3
    const int rb = (t >> 5) * 4;                     // rows rb..rb+3
    const float4* __restrict__ Wv = reinterpret_cast<const float4*>(W);

    float4 acc0 = make_float4(0.f, 0.f, 0.f, 0.f);
    float4 acc1 = acc0, acc2 = acc0, acc3 = acc0;

#pragma unroll 4
    for (int k = 0; k < DIM; ++k) {
        float4 w = Wv[k * 32 + cw];                  // W[k][cw*4..cw*4+3], L1-hot
        float x0 = xs[rb + 0][k];
        float x1 = xs[rb + 1][k];
        float x2 = xs[rb + 2][k];
        float x3 = xs[rb + 3][k];
        acc0.x = fmaf(x0, w.x, acc0.x);
        acc0.y = fmaf(x0, w.y, acc0.y);
        acc0.z = fmaf(x0, w.z, acc0.z);
        acc0.w = fmaf(x0, w.w, acc0.w);
        acc1.x = fmaf(x1, w.x, acc1.x);
        acc1.y = fmaf(x1, w.y, acc1.y);
        acc1.z = fmaf(x1, w.z, acc1.z);
        acc1.w = fmaf(x1, w.w, acc1.w);
        acc2.x = fmaf(x2, w.x, acc2.x);
        acc2.y = fmaf(x2, w.y, acc2.y);
        acc2.z = fmaf(x2, w.z, acc2.z);
        acc2.w = fmaf(x2, w.w, acc2.w);
        acc3.x = fmaf(x3, w.x, acc3.x);
        acc3.y = fmaf(x3, w.y, acc3.y);
        acc3.z = fmaf(x3, w.z, acc3.z);
        acc3.w = fmaf(x3, w.w, acc3.w);
    }

    float4 b4 = *reinterpret_cast<const float4*>(&bias[cw * 4]);
    auto fin = [&](float4 a) {
        a.x += b4.x; a.y += b4.y; a.z += b4.z; a.w += b4.w;
        if (RELU) {
            a.x = fmaxf(a.x, 0.f); a.y = fmaxf(a.y, 0.f);
            a.z = fmaxf(a.z, 0.f); a.w = fmaxf(a.w, 0.f);
        }
        return a;
    };
    size_t o = (size_t)(r0 + rb) * DIM + cw * 4;
    st4(&out[o], fin(acc0));
    st4(&out[o + DIM], fin(acc1));
    st4(&out[o + 2 * DIM], fin(acc2));
    st4(&out[o + 3 * DIM], fin(acc3));
}

// ---------- atomic scatter (fallback for tiny ws) ----------
template <typename ST>
__global__ void scatter_k(const int* __restrict__ src, const int* __restrict__ dst,
                          const float* __restrict__ dinv, const ST* __restrict__ S,
                          float* __restrict__ agg) {
    int i = blockIdx.x * blockDim.x + threadIdx.x;   // grid = NE*32 exactly
    int e = i >> 5;
    int p = (i & 31) * 4;
    int s = src[e], d = dst[e];
    float nrm = dinv[s] * dinv[d];
    float4 hv = ld4(&S[(size_t)s * DIM + p]);
    float* ap = &agg[(size_t)d * DIM + p];
    atomicAdd(ap + 0, hv.x * nrm);
    atomicAdd(ap + 1, hv.y * nrm);
    atomicAdd(ap + 2, hv.z * nrm);
    atomicAdd(ap + 3, hv.w * nrm);
}

// ---------- unfused GEMM (scatter-fallback only) ----------
template <typename ST, typename OT, bool RELU>
__global__ __launch_bounds__(256) void gemm_fused_k(const float* agg, const ST* S,
                                                    const float* __restrict__ dinv,
                                                    const float* __restrict__ W,
                                                    const float* __restrict__ bias,
                                                    OT* out) {
    __shared__ float xs[32][DIM];                    // 16 KB
    const int t = threadIdx.x;
    const int r0 = blockIdx.x * 32;                  // grid = NN/32 exactly

#pragma unroll
    for (int i = 0; i < 4; ++i) {
        int idx = t + i * 256;                       // float4 slot 0..1023
        int rr = idx >> 5;
        int c4 = (idx & 31) * 4;
        int r = r0 + rr;
        float di = dinv[r];
        float d2 = di * di;
        size_t off = (size_t)r * DIM + c4;
        float4 a = *reinterpret_cast<const float4*>(&agg[off]);
        float4 s = ld4(&S[off]);
        xs[rr][c4 + 0] = fmaf(s.x, d2, a.x);
        xs[rr][c4 + 1] = fmaf(s.y, d2, a.y);
        xs[rr][c4 + 2] = fmaf(s.z, d2, a.z);
        xs[rr][c4 + 3] = fmaf(s.w, d2, a.w);
    }
    __syncthreads();

    const int cw = t & 31;
    const int rb = (t >> 5) * 4;
    const float4* __restrict__ Wv = reinterpret_cast<const float4*>(W);

    float4 acc0 = make_float4(0.f, 0.f, 0.f, 0.f);
    float4 acc1 = acc0, acc2 = acc0, acc3 = acc0;

#pragma unroll 4
    for (int k = 0; k < DIM; ++k) {
        float4 w = Wv[k * 32 + cw];
        float x0 = xs[rb + 0][k];
        float x1 = xs[rb + 1][k];
        float x2 = xs[rb + 2][k];
        float x3 = xs[rb + 3][k];
        acc0.x = fmaf(x0, w.x, acc0.x);
        acc0.y = fmaf(x0, w.y, acc0.y);
        acc0.z = fmaf(x0, w.z, acc0.z);
        acc0.w = fmaf(x0, w.w, acc0.w);
        acc1.x = fmaf(x1, w.x, acc1.x);
        acc1.y = fmaf(x1, w.y, acc1.y);
        acc1.z = fmaf(x1, w.z, acc1.z);
        acc1.w = fmaf(x1, w.w, acc1.w);
        acc2.x = fmaf(x2, w.x, acc2.x);
        acc2.y = fmaf(x2, w.y, acc2.y);
        acc2.z = fmaf(x2, w.z, acc2.z);
        acc2.w = fmaf(x2, w.w, acc2.w);
        acc3.x = fmaf(x3, w.x, acc3.x);
        acc3.y = fmaf(x3, w.y, acc3.y);
        acc3.z = fmaf(x3, w.z, acc3.z);
        acc3.w = fmaf(x3, w.w, acc3.w);
    }

    float4 b4 = *reinterpret_cast<const float4*>(&bias[cw * 4]);
    auto fin = [&](float4 a) {
        a.x += b4.x; a.y += b4.y; a.z += b4.z; a.w += b4.w;
        if (RELU) {
            a.x = fmaxf(a.x, 0.f); a.y = fmaxf(a.y, 0.f);
            a.z = fmaxf(a.z, 0.f); a.w = fmaxf(a.w, 0.f);
        }
        return a;
    };
    size_t o = (size_t)(r0 + rb) * DIM + cw * 4;
    st4(&out[o], fin(acc0));
    st4(&out[o + DIM], fin(acc1));
    st4(&out[o + 2 * DIM], fin(acc2));
    st4(&out[o + 3 * DIM], fin(acc3));
}

// ---------- tier-3 utilities ----------
__global__ void compress_k(const float* __restrict__ src, bf16* __restrict__ dst) {
    int i = blockIdx.x * blockDim.x + threadIdx.x;   // grid = NB/256 exactly
    dst[i] = __float2bfloat16(src[i]);
}
__global__ void decomp_k(float* __restrict__ dst, const bf16* __restrict__ src, int n) {
    int i = blockIdx.x * blockDim.x + threadIdx.x;
    if (i < n) dst[i] = __bfloat162float(src[i]);
}

// ---------- driver ----------
// ws layout (CSR mode, needs >= 9 MiB):
//   cnt @0 (400KB) | dinv @512K | row_ptr @1M | cursor @1.5M | bsum/boff @2M
//   csr_src @2.25M (6.4MB) | big @9M (graph-1 bf16 H tier)
// Fallback (ws < 9 MiB): atomic scatter + unfused GEMM, big @1M.
extern "C" void kernel_launch(void* const* d_in, const int* in_sizes, int n_in,
                              void* d_out, int out_size, void* d_ws, size_t ws_size,
                              hipStream_t stream) {
    const float* W0 = (const float*)d_in[4];
    const float* b0 = (const float*)d_in[5];
    const float* W1 = (const float*)d_in[6];
    const float* b1 = (const float*)d_in[7];

    char* ws = (char*)d_ws;
    int*   cnt  = (int*)ws;
    float* dinv = (float*)(ws + (512u << 10));
    int* row_ptr = (int*)(ws + (1u << 20));
    int* cursor  = (int*)(ws + (3u << 19));
    int* bsum    = (int*)(ws + (2u << 20));
    int* boff    = (int*)(ws + (2u << 20) + 4096);
    int* csr_src = (int*)(ws + (9u << 18));          // 2.25 MiB

    const bool csr_ok = ws_size >= (9u << 20);
    char* big = csr_ok ? ws + (9u << 20) : ws + (1u << 20);
    size_t big_avail = ws_size - (csr_ok ? (9u << 20) : (1u << 20));

    const size_t NB = (size_t)NN * DIM;
    float* slot0 = (float*)d_out;
    float* slot1 = slot0 + NB;

    const int SG = (NE * 32) / 256;
    const int GG = NN / 32;                          // 3125
    const int BG = NCHUNK * NSLICE;                  // 1024, sliced build kernels

    auto build = [&](const int* srcp, const int* dstp) {
        hipMemsetAsync(cnt, 0, NN * sizeof(int), stream);
        count_deg_k<<<BG, 256, 0, stream>>>(dstp, cnt);
        dinv_k<<<(NN + 255) / 256, 256, 0, stream>>>(cnt, dinv);
        if (!csr_ok) return;
        blocksum_k<<<NBLK, 256, 0, stream>>>(cnt, bsum);
        scan_bsum_k<<<1, 512, 0, stream>>>(bsum, boff);
        scan_block_k<<<NBLK, 256, 0, stream>>>(cnt, boff, row_ptr, cursor);
        fill_k<<<BG, 256, 0, stream>>>(srcp, dstp, cursor, csr_src);
    };

    if (csr_ok) {
        // ===== graph 0: fused gather+GEMM, h1 bf16 in slot1.lo =====
        {
            const float* x  = (const float*)d_in[0];
            const int*   ei = (const int*)d_in[1];
            bf16* h1b = (bf16*)slot1;                // 25.6 MB
            build(ei, ei + NE);
            fused_gg_k<float, bf16, true><<<GG, 256, 0, stream>>>(
                row_ptr, csr_src, dinv, x, W0, b0, h1b);
            fused_gg_k<bf16, float, false><<<GG, 256, 0, stream>>>(
                row_ptr, csr_src, dinv, h1b, W1, b1, slot0);
        }
        // ===== graph 1 =====
        {
            const float* x  = (const float*)d_in[2];
            const int*   ei = (const int*)d_in[3];
            build(ei, ei + NE);

            if (big_avail >= NB * sizeof(bf16)) {
                // bf16 H in ws
                bf16* H = (bf16*)big;
                fused_gg_k<float, bf16, true><<<GG, 256, 0, stream>>>(
                    row_ptr, csr_src, dinv, x, W0, b0, H);
                fused_gg_k<bf16, float, false><<<GG, 256, 0, stream>>>(
                    row_ptr, csr_src, dinv, H, W1, b1, slot1);
            } else {
                // tier 3: stash g0 as bf16 in slot1.lo, h1 bf16 in slot1.hi
                bf16* g0b = (bf16*)slot1;
                bf16* h1b = (bf16*)((char*)slot1 + NB * sizeof(bf16));
                compress_k<<<(int)(NB / 256), 256, 0, stream>>>(slot0, g0b);
                fused_gg_k<float, bf16, true><<<GG, 256, 0, stream>>>(
                    row_ptr, csr_src, dinv, x, W0, b0, h1b);
                fused_gg_k<bf16, float, false><<<GG, 256, 0, stream>>>(
                    row_ptr, csr_src, dinv, h1b, W1, b1, slot0);
                // swap: slot0 (g1) -> slot1, decompress g0b -> slot0.
                float* stage = (float*)csr_src;      // CSR dead now
                size_t C = 1600000;
                size_t a = NB;
                while (a > 0) {
                    size_t len = (a >= C) ? C : a;
                    a -= len;
                    hipMemcpyAsync(stage, slot0 + a, len * sizeof(float),
                                   hipMemcpyDeviceToDevice, stream);
                    decomp_k<<<(int)((len + 255) / 256), 256, 0, stream>>>(
                        slot0 + a, g0b + a, (int)len);
                    hipMemcpyAsync(slot1 + a, stage, len * sizeof(float),
                                   hipMemcpyDeviceToDevice, stream);
                }
            }
        }
        return;
    }

    // ================= fallback: atomic scatter + unfused GEMM =================
    auto agg_f = [&](const int* srcp, const int* dstp, const float* h, float* agg) {
        hipMemsetAsync(agg, 0, NB * sizeof(float), stream);
        scatter_k<float><<<SG, 256, 0, stream>>>(srcp, dstp, dinv, h, agg);
    };
    auto agg_b = [&](const int* srcp, const int* dstp, const bf16* h, float* agg) {
        hipMemsetAsync(agg, 0, NB * sizeof(float), stream);
        scatter_k<bf16><<<SG, 256, 0, stream>>>(srcp, dstp, dinv, h, agg);
    };

    // graph 0
    {
        const float* x  = (const float*)d_in[0];
        const int*   ei = (const int*)d_in[1];
        bf16* h1b = (bf16*)slot1;
        build(ei, ei + NE);
        agg_f(ei, ei + NE, x, slot0);
        gemm_fused_k<float, bf16, true><<<GG, 256, 0, stream>>>(slot0, x, dinv, W0, b0, h1b);
        agg_b(ei, ei + NE, h1b, slot0);
        gemm_fused_k<bf16, float, false><<<GG, 256, 0, stream>>>(slot0, h1b, dinv, W1, b1, slot0);
    }
    // graph 1
    {
        const float* x  = (const float*)d_in[2];
        const int*   ei = (const int*)d_in[3];
        build(ei, ei + NE);

        // tier 3 (ws < 9 MiB cannot hold bf16 H of 25.6 MB either)
        bf16* g0b = (bf16*)slot1;
        bf16* h1b = (bf16*)((char*)slot1 + NB * sizeof(bf16));
        compress_k<<<(int)(NB / 256), 256, 0, stream>>>(slot0, g0b);
        agg_f(ei, ei + NE, x, slot0);
        gemm_fused_k<float, bf16, true><<<GG, 256, 0, stream>>>(slot0, x, dinv, W0, b0, h1b);
        agg_b(ei, ei + NE, h1b, slot0);
        gemm_fused_k<bf16, float, false><<<GG, 256, 0, stream>>>(slot0, h1b, dinv, W1, b1, slot0);
        float* stage = (float*)big;
        size_t C = (big_avail / sizeof(float)) & ~(size_t)255;
        if (C < 256) C = 256;
        size_t a = NB;
        while (a > 0) {
            size_t len = (a >= C) ? C : a;
            a -= len;
            hipMemcpyAsync(stage, slot0 + a, len * sizeof(float),
                           hipMemcpyDeviceToDevice, stream);
            decomp_k<<<(int)((len + 255) / 256), 256, 0, stream>>>(
                slot0 + a, g0b + a, (int)len);
            hipMemcpyAsync(slot1 + a, stage, len * sizeof(float),
                           hipMemcpyDeviceToDevice, stream);
        }
    }
}

// Round 6
// 1005.716 us; speedup vs baseline: 1.5586x; 1.0656x over previous
//
#include <hip/hip_runtime.h>
#include <hip/hip_bf16.h>

#define NN 100000
#define NE 1600000
#define DIM 128
#define NBLK ((NN + 255) / 256)   // 391

// XCD-sliced CSR build: 8 dst-slices of 12500 nodes, 128 edge-chunks of 12500
#define NSLICE 8
#define SLICE_N 12500             // NN / 8
#define NCHUNK 128
#define CHUNK_E 12500             // NE / 128

using bf16 = __hip_bfloat16;
using bf162 = __hip_bfloat162;

// ---------- dtype helpers ----------
__device__ __forceinline__ float to_f(const float v) { return v; }
__device__ __forceinline__ float to_f(const bf16 v) { return __bfloat162float(v); }

__device__ __forceinline__ float4 ld4(const float* p) {
    return *reinterpret_cast<const float4*>(p);
}
__device__ __forceinline__ float4 ld4(const bf16* p) {
    const bf162* q = reinterpret_cast<const bf162*>(p);
    float2 a = __bfloat1622float2(q[0]);
    float2 b = __bfloat1622float2(q[1]);
    return make_float4(a.x, a.y, b.x, b.y);
}
// 8 consecutive elements -> two float4 (a: cols+0..3, b: cols+4..7)
__device__ __forceinline__ void ld8(const float* p, float4& a, float4& b) {
    a = *reinterpret_cast<const float4*>(p);
    b = *reinterpret_cast<const float4*>(p + 4);
}
__device__ __forceinline__ void ld8(const bf16* p, float4& a, float4& b) {
    float4 r = *reinterpret_cast<const float4*>(p);   // 8 bf16 in one 16B load
    const bf162* q = reinterpret_cast<const bf162*>(&r);
    float2 f0 = __bfloat1622float2(q[0]);
    float2 f1 = __bfloat1622float2(q[1]);
    float2 f2 = __bfloat1622float2(q[2]);
    float2 f3 = __bfloat1622float2(q[3]);
    a = make_float4(f0.x, f0.y, f1.x, f1.y);
    b = make_float4(f2.x, f2.y, f3.x, f3.y);
}
__device__ __forceinline__ void st1(float* p, float v) { *p = v; }
__device__ __forceinline__ void st1(bf16* p, float v) { *p = __float2bfloat16(v); }
__device__ __forceinline__ void st4(float* p, float4 v) {
    *reinterpret_cast<float4*>(p) = v;
}
__device__ __forceinline__ void st4(bf16* p, float4 v) {
    bf162* q = reinterpret_cast<bf162*>(p);
    q[0] = __float22bfloat162_rn(make_float2(v.x, v.y));
    q[1] = __float22bfloat162_rn(make_float2(v.z, v.w));
}

// ---------- degree / normalization ----------
// XCD-sliced: blockIdx&7 selects a dst-slice (lands on one XCD under
// round-robin dispatch) -> atomic working set per XCD is L2-local.
__global__ __launch_bounds__(256) void count_deg_k(const int* __restrict__ dst,
                                                   int* __restrict__ cnt) {
    const int s = blockIdx.x & 7;
    const int c = blockIdx.x >> 3;                   // grid = NCHUNK*8
    const int lo = s * SLICE_N;
    const int beg = c * CHUNK_E, end = beg + CHUNK_E;
    for (int e = beg + threadIdx.x; e < end; e += 256) {
        int d = dst[e];
        if ((unsigned)(d - lo) < (unsigned)SLICE_N) atomicAdd(&cnt[d], 1);
    }
}

__global__ void dinv_k(const int* __restrict__ cnt, float* __restrict__ dinv) {
    int i = blockIdx.x * blockDim.x + threadIdx.x;
    if (i < NN) dinv[i] = rsqrtf((float)cnt[i] + 1.0f);   // +1 self-loop
}

// ---------- CSR build: two-level exclusive scan + cursor fill ----------
__global__ void blocksum_k(const int* __restrict__ cnt, int* __restrict__ bsum) {
    __shared__ int s[256];
    int i = blockIdx.x * 256 + threadIdx.x;
    s[threadIdx.x] = (i < NN) ? cnt[i] : 0;
    __syncthreads();
    for (int off = 128; off > 0; off >>= 1) {
        if (threadIdx.x < off) s[threadIdx.x] += s[threadIdx.x + off];
        __syncthreads();
    }
    if (threadIdx.x == 0) bsum[blockIdx.x] = s[0];
}

__global__ void scan_bsum_k(const int* __restrict__ bsum, int* __restrict__ boff) {
    __shared__ int s[512];                           // 1 block of 512 covers NBLK=391
    int t = threadIdx.x;
    int v = (t < NBLK) ? bsum[t] : 0;
    s[t] = v;
    __syncthreads();
    for (int off = 1; off < 512; off <<= 1) {
        int tmp = (t >= off) ? s[t - off] : 0;
        __syncthreads();
        s[t] += tmp;
        __syncthreads();
    }
    if (t < NBLK) boff[t] = s[t] - v;                // exclusive
}

__global__ void scan_block_k(const int* __restrict__ cnt, const int* __restrict__ boff,
                             int* __restrict__ row_ptr, int* __restrict__ cursor) {
    __shared__ int s[256];
    int t = threadIdx.x, i = blockIdx.x * 256 + t;
    int v = (i < NN) ? cnt[i] : 0;
    s[t] = v;
    __syncthreads();
    for (int off = 1; off < 256; off <<= 1) {
        int tmp = (t >= off) ? s[t - off] : 0;
        __syncthreads();
        s[t] += tmp;
        __syncthreads();
    }
    if (i < NN) {
        int e = boff[blockIdx.x] + s[t] - v;         // global exclusive
        row_ptr[i] = e;
        cursor[i] = e;
    }
    if (i == NN - 1) row_ptr[NN] = NE;
}

// XCD-sliced cursor fill (same slicing as count_deg_k): per-slice csr_src
// region is ~0.8 MB -> one XCD's L2, write amplification ~1.
__global__ __launch_bounds__(256) void fill_k(const int* __restrict__ src,
                                              const int* __restrict__ dst,
                                              int* __restrict__ cursor,
                                              int* __restrict__ csr_src) {
    const int s = blockIdx.x & 7;
    const int c = blockIdx.x >> 3;                   // grid = NCHUNK*8
    const int lo = s * SLICE_N;
    const int beg = c * CHUNK_E, end = beg + CHUNK_E;
    for (int e = beg + threadIdx.x; e < end; e += 256) {
        int d = dst[e];
        if ((unsigned)(d - lo) < (unsigned)SLICE_N) {
            int pos = atomicAdd(&cursor[d], 1);
            csr_src[pos] = src[e];
        }
    }
}

// ---------- FUSED gather + GEMM ----------
// out[r] = act( (dd*sum_{s in N(r)} dinv[s]*h[s] + dd^2*h[r]) @ W + b )
// Block = 32 nodes (grid NN/32). Phase 1 v3: 4 quarter-waves process 4 edges
// concurrently (q = lane>>4 selects edge, m = lane&15 selects col octet);
// main loop covers 8 edges/iteration with all loads issued in one basic block
// -> 2-4 independent loads in flight per lane (v2 had ~1: latency-bound,
// 2.5 TB/s observed). Cross-quarter reduce via shfl_xor(16|32). Phase 2:
// register-blocked GEMM, W from global (L1/L2-hot). No global agg round-trip.
template <typename ST, typename OT, bool RELU>
__global__ __launch_bounds__(256) void fused_gg_k(const int* __restrict__ row_ptr,
                                                  const int* __restrict__ csr_src,
                                                  const float* __restrict__ dinv,
                                                  const ST* __restrict__ h,
                                                  const float* __restrict__ W,
                                                  const float* __restrict__ bias,
                                                  OT* __restrict__ out) {
    __shared__ float xs[32][DIM];                    // 16 KB
    const int t = threadIdx.x;
    const int r0 = blockIdx.x * 32;                  // grid = NN/32 exactly
    const int wv = t >> 6;                           // wave 0..3
    const int lane = t & 63;
    const int q = lane >> 4;                         // edge slot 0..3
    const int m = lane & 15;                         // col octet: cols m*8..m*8+7

    // ---- phase 1: gather 8 nodes per wave ----
    for (int i = 0; i < 8; ++i) {
        const int nd = r0 + wv * 8 + i;
        const int beg = row_ptr[nd], end = row_ptr[nd + 1];
        const float dd = dinv[nd];
        float4 A0 = make_float4(0.f, 0.f, 0.f, 0.f);
        float4 A1 = A0;
        for (int base = beg; base < end; base += 64) {
            int k = end - base;
            if (k > 64) k = 64;
            int s = 0;
            float ns = 0.f;
            if (lane < k) { s = csr_src[base + lane]; ns = dinv[s]; }
            const int kfull = k & ~7;
            // hot path: 8 edges per iteration, 2 independent loads per lane
            for (int j = 0; j < kfull; j += 8) {
                int   s0 = __shfl(s,  j + q);
                float n0 = __shfl(ns, j + q);
                int   s1 = __shfl(s,  j + 4 + q);
                float n1 = __shfl(ns, j + 4 + q);
                float4 a0, b0, a1, b1;
                ld8(&h[(size_t)s0 * DIM + m * 8], a0, b0);
                ld8(&h[(size_t)s1 * DIM + m * 8], a1, b1);
                A0.x = fmaf(a0.x, n0, A0.x);
                A0.y = fmaf(a0.y, n0, A0.y);
                A0.z = fmaf(a0.z, n0, A0.z);
                A0.w = fmaf(a0.w, n0, A0.w);
                A1.x = fmaf(b0.x, n0, A1.x);
                A1.y = fmaf(b0.y, n0, A1.y);
                A1.z = fmaf(b0.z, n0, A1.z);
                A1.w = fmaf(b0.w, n0, A1.w);
                A0.x = fmaf(a1.x, n1, A0.x);
                A0.y = fmaf(a1.y, n1, A0.y);
                A0.z = fmaf(a1.z, n1, A0.z);
                A0.w = fmaf(a1.w, n1, A0.w);
                A1.x = fmaf(b1.x, n1, A1.x);
                A1.y = fmaf(b1.y, n1, A1.y);
                A1.z = fmaf(b1.z, n1, A1.z);
                A1.w = fmaf(b1.w, n1, A1.w);
            }
            // tail: 1..7 edges (shfl from lanes >= k yields s=0/ns=0 -> no-op)
            if (kfull < k) {
                int   s0 = __shfl(s,  kfull + q);
                float n0 = __shfl(ns, kfull + q);
                float4 a0, b0;
                ld8(&h[(size_t)s0 * DIM + m * 8], a0, b0);
                if (kfull + 4 < k) {                 // wave-uniform branch
                    int   s1 = __shfl(s,  kfull + 4 + q);
                    float n1 = __shfl(ns, kfull + 4 + q);
                    float4 a1, b1;
                    ld8(&h[(size_t)s1 * DIM + m * 8], a1, b1);
                    A0.x = fmaf(a1.x, n1, A0.x);
                    A0.y = fmaf(a1.y, n1, A0.y);
                    A0.z = fmaf(a1.z, n1, A0.z);
                    A0.w = fmaf(a1.w, n1, A0.w);
                    A1.x = fmaf(b1.x, n1, A1.x);
                    A1.y = fmaf(b1.y, n1, A1.y);
                    A1.z = fmaf(b1.z, n1, A1.z);
                    A1.w = fmaf(b1.w, n1, A1.w);
                }
                A0.x = fmaf(a0.x, n0, A0.x);
                A0.y = fmaf(a0.y, n0, A0.y);
                A0.z = fmaf(a0.z, n0, A0.z);
                A0.w = fmaf(a0.w, n0, A0.w);
                A1.x = fmaf(b0.x, n0, A1.x);
                A1.y = fmaf(b0.y, n0, A1.y);
                A1.z = fmaf(b0.z, n0, A1.z);
                A1.w = fmaf(b0.w, n0, A1.w);
            }
        }
        // cross-quarter reduce: xor 16 then xor 32 -> every lane holds full sum
        A0.x += __shfl_xor(A0.x, 16); A0.y += __shfl_xor(A0.y, 16);
        A0.z += __shfl_xor(A0.z, 16); A0.w += __shfl_xor(A0.w, 16);
        A1.x += __shfl_xor(A1.x, 16); A1.y += __shfl_xor(A1.y, 16);
        A1.z += __shfl_xor(A1.z, 16); A1.w += __shfl_xor(A1.w, 16);
        A0.x += __shfl_xor(A0.x, 32); A0.y += __shfl_xor(A0.y, 32);
        A0.z += __shfl_xor(A0.z, 32); A0.w += __shfl_xor(A0.w, 32);
        A1.x += __shfl_xor(A1.x, 32); A1.y += __shfl_xor(A1.y, 32);
        A1.z += __shfl_xor(A1.z, 32); A1.w += __shfl_xor(A1.w, 32);
        if (q == 0) {
            float4 sa, sb;
            ld8(&h[(size_t)nd * DIM + m * 8], sa, sb);   // self row
            float d2 = dd * dd;
            float4 v0 = make_float4(fmaf(sa.x, d2, A0.x * dd),
                                    fmaf(sa.y, d2, A0.y * dd),
                                    fmaf(sa.z, d2, A0.z * dd),
                                    fmaf(sa.w, d2, A0.w * dd));
            float4 v1 = make_float4(fmaf(sb.x, d2, A1.x * dd),
                                    fmaf(sb.y, d2, A1.y * dd),
                                    fmaf(sb.z, d2, A1.z * dd),
                                    fmaf(sb.w, d2, A1.w * dd));
            *reinterpret_cast<float4*>(&xs[wv * 8 + i][m * 8]) = v0;
            *reinterpret_cast<float4*>(&xs[wv * 8 + i][m * 8 + 4]) = v1;
        }
    }
    __syncthreads();

    // ---- phase 2: GEMM (register-blocked, 4x4 tile/thread) ----
    const int cw = t & 31;                           // cols cw*4..cw*4+3
    const int rb = (t >> 5) * 4;                     // rows rb..rb+3
    const float4* __restrict__ Wv = reinterpret_cast<const float4*>(W);

    float4 acc0 = make_float4(0.f, 0.f, 0.f, 0.f);
    float4 acc1 = acc0, acc2 = acc0, acc3 = acc0;

#pragma unroll 4
    for (int k = 0; k < DIM; ++k) {
        float4 w = Wv[k * 32 + cw];                  // W[k][cw*4..cw*4+3], L1-hot
        float x0 = xs[rb + 0][k];
        float x1 = xs[rb + 1][k];
        float x2 = xs[rb + 2][k];
        float x3 = xs[rb + 3][k];
        acc0.x = fmaf(x0, w.x, acc0.x);
        acc0.y = fmaf(x0, w.y, acc0.y);
        acc0.z = fmaf(x0, w.z, acc0.z);
        acc0.w = fmaf(x0, w.w, acc0.w);
        acc1.x = fmaf(x1, w.x, acc1.x);
        acc1.y = fmaf(x1, w.y, acc1.y);
        acc1.z = fmaf(x1, w.z, acc1.z);
        acc1.w = fmaf(x1, w.w, acc1.w);
        acc2.x = fmaf(x2, w.x, acc2.x);
        acc2.y = fmaf(x2, w.y, acc2.y);
        acc2.z = fmaf(x2, w.z, acc2.z);
        acc2.w = fmaf(x2, w.w, acc2.w);
        acc3.x = fmaf(x3, w.x, acc3.x);
        acc3.y = fmaf(x3, w.y, acc3.y);
        acc3.z = fmaf(x3, w.z, acc3.z);
        acc3.w = fmaf(x3, w.w, acc3.w);
    }

    float4 b4 = *reinterpret_cast<const float4*>(&bias[cw * 4]);
    auto fin = [&](float4 a) {
        a.x += b4.x; a.y += b4.y; a.z += b4.z; a.w += b4.w;
        if (RELU) {
            a.x = fmaxf(a.x, 0.f); a.y = fmaxf(a.y, 0.f);
            a.z = fmaxf(a.z, 0.f); a.w = fmaxf(a.w, 0.f);
        }
        return a;
    };
    size_t o = (size_t)(r0 + rb) * DIM + cw * 4;
    st4(&out[o], fin(acc0));
    st4(&out[o + DIM], fin(acc1));
    st4(&out[o + 2 * DIM], fin(acc2));
    st4(&out[o + 3 * DIM], fin(acc3));
}

// ---------- atomic scatter (fallback for tiny ws) ----------
template <typename ST>
__global__ void scatter_k(const int* __restrict__ src, const int* __restrict__ dst,
                          const float* __restrict__ dinv, const ST* __restrict__ S,
                          float* __restrict__ agg) {
    int i = blockIdx.x * blockDim.x + threadIdx.x;   // grid = NE*32 exactly
    int e = i >> 5;
    int p = (i & 31) * 4;
    int s = src[e], d = dst[e];
    float nrm = dinv[s] * dinv[d];
    float4 hv = ld4(&S[(size_t)s * DIM + p]);
    float* ap = &agg[(size_t)d * DIM + p];
    atomicAdd(ap + 0, hv.x * nrm);
    atomicAdd(ap + 1, hv.y * nrm);
    atomicAdd(ap + 2, hv.z * nrm);
    atomicAdd(ap + 3, hv.w * nrm);
}

// ---------- unfused GEMM (scatter-fallback only) ----------
template <typename ST, typename OT, bool RELU>
__global__ __launch_bounds__(256) void gemm_fused_k(const float* agg, const ST* S,
                                                    const float* __restrict__ dinv,
                                                    const float* __restrict__ W,
                                                    const float* __restrict__ bias,
                                                    OT* out) {
    __shared__ float xs[32][DIM];                    // 16 KB
    const int t = threadIdx.x;
    const int r0 = blockIdx.x * 32;                  // grid = NN/32 exactly

#pragma unroll
    for (int i = 0; i < 4; ++i) {
        int idx = t + i * 256;                       // float4 slot 0..1023
        int rr = idx >> 5;
        int c4 = (idx & 31) * 4;
        int r = r0 + rr;
        float di = dinv[r];
        float d2 = di * di;
        size_t off = (size_t)r * DIM + c4;
        float4 a = *reinterpret_cast<const float4*>(&agg[off]);
        float4 s = ld4(&S[off]);
        xs[rr][c4 + 0] = fmaf(s.x, d2, a.x);
        xs[rr][c4 + 1] = fmaf(s.y, d2, a.y);
        xs[rr][c4 + 2] = fmaf(s.z, d2, a.z);
        xs[rr][c4 + 3] = fmaf(s.w, d2, a.w);
    }
    __syncthreads();

    const int cw = t & 31;
    const int rb = (t >> 5) * 4;
    const float4* __restrict__ Wv = reinterpret_cast<const float4*>(W);

    float4 acc0 = make_float4(0.f, 0.f, 0.f, 0.f);
    float4 acc1 = acc0, acc2 = acc0, acc3 = acc0;

#pragma unroll 4
    for (int k = 0; k < DIM; ++k) {
        float4 w = Wv[k * 32 + cw];
        float x0 = xs[rb + 0][k];
        float x1 = xs[rb + 1][k];
        float x2 = xs[rb + 2][k];
        float x3 = xs[rb + 3][k];
        acc0.x = fmaf(x0, w.x, acc0.x);
        acc0.y = fmaf(x0, w.y, acc0.y);
        acc0.z = fmaf(x0, w.z, acc0.z);
        acc0.w = fmaf(x0, w.w, acc0.w);
        acc1.x = fmaf(x1, w.x, acc1.x);
        acc1.y = fmaf(x1, w.y, acc1.y);
        acc1.z = fmaf(x1, w.z, acc1.z);
        acc1.w = fmaf(x1, w.w, acc1.w);
        acc2.x = fmaf(x2, w.x, acc2.x);
        acc2.y = fmaf(x2, w.y, acc2.y);
        acc2.z = fmaf(x2, w.z, acc2.z);
        acc2.w = fmaf(x2, w.w, acc2.w);
        acc3.x = fmaf(x3, w.x, acc3.x);
        acc3.y = fmaf(x3, w.y, acc3.y);
        acc3.z = fmaf(x3, w.z, acc3.z);
        acc3.w = fmaf(x3, w.w, acc3.w);
    }

    float4 b4 = *reinterpret_cast<const float4*>(&bias[cw * 4]);
    auto fin = [&](float4 a) {
        a.x += b4.x; a.y += b4.y; a.z += b4.z; a.w += b4.w;
        if (RELU) {
            a.x = fmaxf(a.x, 0.f); a.y = fmaxf(a.y, 0.f);
            a.z = fmaxf(a.z, 0.f); a.w = fmaxf(a.w, 0.f);
        }
        return a;
    };
    size_t o = (size_t)(r0 + rb) * DIM + cw * 4;
    st4(&out[o], fin(acc0));
    st4(&out[o + DIM], fin(acc1));
    st4(&out[o + 2 * DIM], fin(acc2));
    st4(&out[o + 3 * DIM], fin(acc3));
}

// ---------- tier-3 utilities ----------
__global__ void compress_k(const float* __restrict__ src, bf16* __restrict__ dst) {
    int i = blockIdx.x * blockDim.x + threadIdx.x;   // grid = NB/256 exactly
    dst[i] = __float2bfloat16(src[i]);
}
__global__ void decomp_k(float* __restrict__ dst, const bf16* __restrict__ src, int n) {
    int i = blockIdx.x * blockDim.x + threadIdx.x;
    if (i < n) dst[i] = __bfloat162float(src[i]);
}

// ---------- driver ----------
// ws layout (CSR mode, needs >= 9 MiB):
//   cnt @0 (400KB) | dinv @512K | row_ptr @1M | cursor @1.5M | bsum/boff @2M
//   csr_src @2.25M (6.4MB) | big @9M (graph-1 bf16 H tier)
// Fallback (ws < 9 MiB): atomic scatter + unfused GEMM, big @1M.
extern "C" void kernel_launch(void* const* d_in, const int* in_sizes, int n_in,
                              void* d_out, int out_size, void* d_ws, size_t ws_size,
                              hipStream_t stream) {
    const float* W0 = (const float*)d_in[4];
    const float* b0 = (const float*)d_in[5];
    const float* W1 = (const float*)d_in[6];
    const float* b1 = (const float*)d_in[7];

    char* ws = (char*)d_ws;
    int*   cnt  = (int*)ws;
    float* dinv = (float*)(ws + (512u << 10));
    int* row_ptr = (int*)(ws + (1u << 20));
    int* cursor  = (int*)(ws + (3u << 19));
    int* bsum    = (int*)(ws + (2u << 20));
    int* boff    = (int*)(ws + (2u << 20) + 4096);
    int* csr_src = (int*)(ws + (9u << 18));          // 2.25 MiB

    const bool csr_ok = ws_size >= (9u << 20);
    char* big = csr_ok ? ws + (9u << 20) : ws + (1u << 20);
    size_t big_avail = ws_size - (csr_ok ? (9u << 20) : (1u << 20));

    const size_t NB = (size_t)NN * DIM;
    float* slot0 = (float*)d_out;
    float* slot1 = slot0 + NB;

    const int SG = (NE * 32) / 256;
    const int GG = NN / 32;                          // 3125
    const int BG = NCHUNK * NSLICE;                  // 1024, sliced build kernels

    auto build = [&](const int* srcp, const int* dstp) {
        hipMemsetAsync(cnt, 0, NN * sizeof(int), stream);
        count_deg_k<<<BG, 256, 0, stream>>>(dstp, cnt);
        dinv_k<<<(NN + 255) / 256, 256, 0, stream>>>(cnt, dinv);
        if (!csr_ok) return;
        blocksum_k<<<NBLK, 256, 0, stream>>>(cnt, bsum);
        scan_bsum_k<<<1, 512, 0, stream>>>(bsum, boff);
        scan_block_k<<<NBLK, 256, 0, stream>>>(cnt, boff, row_ptr, cursor);
        fill_k<<<BG, 256, 0, stream>>>(srcp, dstp, cursor, csr_src);
    };

    if (csr_ok) {
        // ===== graph 0: fused gather+GEMM, h1 bf16 in slot1.lo =====
        {
            const float* x  = (const float*)d_in[0];
            const int*   ei = (const int*)d_in[1];
            bf16* h1b = (bf16*)slot1;                // 25.6 MB
            build(ei, ei + NE);
            fused_gg_k<float, bf16, true><<<GG, 256, 0, stream>>>(
                row_ptr, csr_src, dinv, x, W0, b0, h1b);
            fused_gg_k<bf16, float, false><<<GG, 256, 0, stream>>>(
                row_ptr, csr_src, dinv, h1b, W1, b1, slot0);
        }
        // ===== graph 1 =====
        {
            const float* x  = (const float*)d_in[2];
            const int*   ei = (const int*)d_in[3];
            build(ei, ei + NE);

            if (big_avail >= NB * sizeof(bf16)) {
                // bf16 H in ws
                bf16* H = (bf16*)big;
                fused_gg_k<float, bf16, true><<<GG, 256, 0, stream>>>(
                    row_ptr, csr_src, dinv, x, W0, b0, H);
                fused_gg_k<bf16, float, false><<<GG, 256, 0, stream>>>(
                    row_ptr, csr_src, dinv, H, W1, b1, slot1);
            } else {
                // tier 3: stash g0 as bf16 in slot1.lo, h1 bf16 in slot1.hi
                bf16* g0b = (bf16*)slot1;
                bf16* h1b = (bf16*)((char*)slot1 + NB * sizeof(bf16));
                compress_k<<<(int)(NB / 256), 256, 0, stream>>>(slot0, g0b);
                fused_gg_k<float, bf16, true><<<GG, 256, 0, stream>>>(
                    row_ptr, csr_src, dinv, x, W0, b0, h1b);
                fused_gg_k<bf16, float, false><<<GG, 256, 0, stream>>>(
                    row_ptr, csr_src, dinv, h1b, W1, b1, slot0);
                // swap: slot0 (g1) -> slot1, decompress g0b -> slot0.
                float* stage = (float*)csr_src;      // CSR dead now
                size_t C = 1600000;
                size_t a = NB;
                while (a > 0) {
                    size_t len = (a >= C) ? C : a;
                    a -= len;
                    hipMemcpyAsync(stage, slot0 + a, len * sizeof(float),
                                   hipMemcpyDeviceToDevice, stream);
                    decomp_k<<<(int)((len + 255) / 256), 256, 0, stream>>>(
                        slot0 + a, g0b + a, (int)len);
                    hipMemcpyAsync(slot1 + a, stage, len * sizeof(float),
                                   hipMemcpyDeviceToDevice, stream);
                }
            }
        }
        return;
    }

    // ================= fallback: atomic scatter + unfused GEMM =================
    auto agg_f = [&](const int* srcp, const int* dstp, const float* h, float* agg) {
        hipMemsetAsync(agg, 0, NB * sizeof(float), stream);
        scatter_k<float><<<SG, 256, 0, stream>>>(srcp, dstp, dinv, h, agg);
    };
    auto agg_b = [&](const int* srcp, const int* dstp, const bf16* h, float* agg) {
        hipMemsetAsync(agg, 0, NB * sizeof(float), stream);
        scatter_k<bf16><<<SG, 256, 0, stream>>>(srcp, dstp, dinv, h, agg);
    };

    // graph 0
    {
        const float* x  = (const float*)d_in[0];
        const int*   ei = (const int*)d_in[1];
        bf16* h1b = (bf16*)slot1;
        build(ei, ei + NE);
        agg_f(ei, ei + NE, x, slot0);
        gemm_fused_k<float, bf16, true><<<GG, 256, 0, stream>>>(slot0, x, dinv, W0, b0, h1b);
        agg_b(ei, ei + NE, h1b, slot0);
        gemm_fused_k<bf16, float, false><<<GG, 256, 0, stream>>>(slot0, h1b, dinv, W1, b1, slot0);
    }
    // graph 1
    {
        const float* x  = (const float*)d_in[2];
        const int*   ei = (const int*)d_in[3];
        build(ei, ei + NE);

        // tier 3 (ws < 9 MiB cannot hold bf16 H of 25.6 MB either)
        bf16* g0b = (bf16*)slot1;
        bf16* h1b = (bf16*)((char*)slot1 + NB * sizeof(bf16));
        compress_k<<<(int)(NB / 256), 256, 0, stream>>>(slot0, g0b);
        agg_f(ei, ei + NE, x, slot0);
        gemm_fused_k<float, bf16, true><<<GG, 256, 0, stream>>>(slot0, x, dinv, W0, b0, h1b);
        agg_b(ei, ei + NE, h1b, slot0);
        gemm_fused_k<bf16, float, false><<<GG, 256, 0, stream>>>(slot0, h1b, dinv, W1, b1, slot0);
        float* stage = (float*)big;
        size_t C = (big_avail / sizeof(float)) & ~(size_t)255;
        if (C < 256) C = 256;
        size_t a = NB;
        while (a > 0) {
            size_t len = (a >= C) ? C : a;
            a -= len;
            hipMemcpyAsync(stage, slot0 + a, len * sizeof(float),
                           hipMemcpyDeviceToDevice, stream);
            decomp_k<<<(int)((len + 255) / 256), 256, 0, stream>>>(
                slot0 + a, g0b + a, (int)len);
            hipMemcpyAsync(slot1 + a, stage, len * sizeof(float),
                           hipMemcpyDeviceToDevice, stream);
        }
    }
}

// Round 7
// 946.492 us; speedup vs baseline: 1.6561x; 1.0626x over previous
//
#include <hip/hip_runtime.h>
#include <hip/hip_bf16.h>

#define NN 100000
#define NE 1600000
#define DIM 128
#define NBLK ((NN + 255) / 256)   // 391

// XCD-sliced CSR build: 8 dst-slices of 12500 nodes, 128 edge-chunks of 12500
#define NSLICE 8
#define SLICE_N 12500             // NN / 8
#define NCHUNK 128
#define CHUNK_E 12500             // NE / 128

using bf16 = __hip_bfloat16;
using bf162 = __hip_bfloat162;

// ---------- dtype helpers ----------
__device__ __forceinline__ float to_f(const float v) { return v; }
__device__ __forceinline__ float to_f(const bf16 v) { return __bfloat162float(v); }

__device__ __forceinline__ float4 ld4(const float* p) {
    return *reinterpret_cast<const float4*>(p);
}
__device__ __forceinline__ float4 ld4(const bf16* p) {
    const bf162* q = reinterpret_cast<const bf162*>(p);
    float2 a = __bfloat1622float2(q[0]);
    float2 b = __bfloat1622float2(q[1]);
    return make_float4(a.x, a.y, b.x, b.y);
}
// 8 consecutive elements -> two float4 (a: cols+0..3, b: cols+4..7)
__device__ __forceinline__ void ld8(const float* p, float4& a, float4& b) {
    a = *reinterpret_cast<const float4*>(p);
    b = *reinterpret_cast<const float4*>(p + 4);
}
__device__ __forceinline__ void ld8(const bf16* p, float4& a, float4& b) {
    float4 r = *reinterpret_cast<const float4*>(p);   // 8 bf16 in one 16B load
    const bf162* q = reinterpret_cast<const bf162*>(&r);
    float2 f0 = __bfloat1622float2(q[0]);
    float2 f1 = __bfloat1622float2(q[1]);
    float2 f2 = __bfloat1622float2(q[2]);
    float2 f3 = __bfloat1622float2(q[3]);
    a = make_float4(f0.x, f0.y, f1.x, f1.y);
    b = make_float4(f2.x, f2.y, f3.x, f3.y);
}
__device__ __forceinline__ void st1(float* p, float v) { *p = v; }
__device__ __forceinline__ void st1(bf16* p, float v) { *p = __float2bfloat16(v); }
__device__ __forceinline__ void st4(float* p, float4 v) {
    *reinterpret_cast<float4*>(p) = v;
}
__device__ __forceinline__ void st4(bf16* p, float4 v) {
    bf162* q = reinterpret_cast<bf162*>(p);
    q[0] = __float22bfloat162_rn(make_float2(v.x, v.y));
    q[1] = __float22bfloat162_rn(make_float2(v.z, v.w));
}

// ---------- degree / normalization ----------
// XCD-sliced: blockIdx&7 selects a dst-slice (lands on one XCD under
// round-robin dispatch) -> atomic working set per XCD is L2-local.
__global__ __launch_bounds__(256) void count_deg_k(const int* __restrict__ dst,
                                                   int* __restrict__ cnt) {
    const int s = blockIdx.x & 7;
    const int c = blockIdx.x >> 3;                   // grid = NCHUNK*8
    const int lo = s * SLICE_N;
    const int beg = c * CHUNK_E, end = beg + CHUNK_E;
    for (int e = beg + threadIdx.x; e < end; e += 256) {
        int d = dst[e];
        if ((unsigned)(d - lo) < (unsigned)SLICE_N) atomicAdd(&cnt[d], 1);
    }
}

__global__ void dinv_k(const int* __restrict__ cnt, float* __restrict__ dinv) {
    int i = blockIdx.x * blockDim.x + threadIdx.x;
    if (i < NN) dinv[i] = rsqrtf((float)cnt[i] + 1.0f);   // +1 self-loop
}

// ---------- CSR build: two-level exclusive scan + cursor fill ----------
__global__ void blocksum_k(const int* __restrict__ cnt, int* __restrict__ bsum) {
    __shared__ int s[256];
    int i = blockIdx.x * 256 + threadIdx.x;
    s[threadIdx.x] = (i < NN) ? cnt[i] : 0;
    __syncthreads();
    for (int off = 128; off > 0; off >>= 1) {
        if (threadIdx.x < off) s[threadIdx.x] += s[threadIdx.x + off];
        __syncthreads();
    }
    if (threadIdx.x == 0) bsum[blockIdx.x] = s[0];
}

__global__ void scan_bsum_k(const int* __restrict__ bsum, int* __restrict__ boff) {
    __shared__ int s[512];                           // 1 block of 512 covers NBLK=391
    int t = threadIdx.x;
    int v = (t < NBLK) ? bsum[t] : 0;
    s[t] = v;
    __syncthreads();
    for (int off = 1; off < 512; off <<= 1) {
        int tmp = (t >= off) ? s[t - off] : 0;
        __syncthreads();
        s[t] += tmp;
        __syncthreads();
    }
    if (t < NBLK) boff[t] = s[t] - v;                // exclusive
}

__global__ void scan_block_k(const int* __restrict__ cnt, const int* __restrict__ boff,
                             int* __restrict__ row_ptr, int* __restrict__ cursor) {
    __shared__ int s[256];
    int t = threadIdx.x, i = blockIdx.x * 256 + t;
    int v = (i < NN) ? cnt[i] : 0;
    s[t] = v;
    __syncthreads();
    for (int off = 1; off < 256; off <<= 1) {
        int tmp = (t >= off) ? s[t - off] : 0;
        __syncthreads();
        s[t] += tmp;
        __syncthreads();
    }
    if (i < NN) {
        int e = boff[blockIdx.x] + s[t] - v;         // global exclusive
        row_ptr[i] = e;
        cursor[i] = e;
    }
    if (i == NN - 1) row_ptr[NN] = NE;
}

// XCD-sliced cursor fill (same slicing as count_deg_k): per-slice csr_src
// region is ~0.8 MB -> one XCD's L2, write amplification ~1.
__global__ __launch_bounds__(256) void fill_k(const int* __restrict__ src,
                                              const int* __restrict__ dst,
                                              int* __restrict__ cursor,
                                              int* __restrict__ csr_src) {
    const int s = blockIdx.x & 7;
    const int c = blockIdx.x >> 3;                   // grid = NCHUNK*8
    const int lo = s * SLICE_N;
    const int beg = c * CHUNK_E, end = beg + CHUNK_E;
    for (int e = beg + threadIdx.x; e < end; e += 256) {
        int d = dst[e];
        if ((unsigned)(d - lo) < (unsigned)SLICE_N) {
            int pos = atomicAdd(&cursor[d], 1);
            csr_src[pos] = src[e];
        }
    }
}

// ---------- FUSED gather + GEMM ----------
// out[r] = act( (dd*sum_{s in N(r)} dinv[s]*h[s] + dd^2*h[r]) @ W + b )
// Block = 32 nodes (grid NN/32). Phase 1: 4 quarter-waves process 4 edges
// concurrently (q = lane>>4 selects edge, m = lane&15 selects col octet);
// 8 edges/iteration, loads issued back-to-back. Gather table h is bf16 in
// steady state (fabric random-read ceiling ~2.7 TB/s observed -> halve bytes:
// fp32 table = 8 XCD x 51 MB = 419 MB FETCH; bf16 = ~215 MB). Phase 2:
// register-blocked GEMM, W from global (L1/L2-hot). No global agg round-trip.
template <typename ST, typename OT, bool RELU>
__global__ __launch_bounds__(256) void fused_gg_k(const int* __restrict__ row_ptr,
                                                  const int* __restrict__ csr_src,
                                                  const float* __restrict__ dinv,
                                                  const ST* __restrict__ h,
                                                  const float* __restrict__ W,
                                                  const float* __restrict__ bias,
                                                  OT* __restrict__ out) {
    __shared__ float xs[32][DIM];                    // 16 KB
    const int t = threadIdx.x;
    const int r0 = blockIdx.x * 32;                  // grid = NN/32 exactly
    const int wv = t >> 6;                           // wave 0..3
    const int lane = t & 63;
    const int q = lane >> 4;                         // edge slot 0..3
    const int m = lane & 15;                         // col octet: cols m*8..m*8+7

    // ---- phase 1: gather 8 nodes per wave ----
    for (int i = 0; i < 8; ++i) {
        const int nd = r0 + wv * 8 + i;
        const int beg = row_ptr[nd], end = row_ptr[nd + 1];
        const float dd = dinv[nd];
        float4 A0 = make_float4(0.f, 0.f, 0.f, 0.f);
        float4 A1 = A0;
        for (int base = beg; base < end; base += 64) {
            int k = end - base;
            if (k > 64) k = 64;
            int s = 0;
            float ns = 0.f;
            if (lane < k) { s = csr_src[base + lane]; ns = dinv[s]; }
            const int kfull = k & ~7;
            // hot path: 8 edges per iteration
            for (int j = 0; j < kfull; j += 8) {
                int   s0 = __shfl(s,  j + q);
                float n0 = __shfl(ns, j + q);
                int   s1 = __shfl(s,  j + 4 + q);
                float n1 = __shfl(ns, j + 4 + q);
                float4 a0, b0, a1, b1;
                ld8(&h[(size_t)s0 * DIM + m * 8], a0, b0);
                ld8(&h[(size_t)s1 * DIM + m * 8], a1, b1);
                A0.x = fmaf(a0.x, n0, A0.x);
                A0.y = fmaf(a0.y, n0, A0.y);
                A0.z = fmaf(a0.z, n0, A0.z);
                A0.w = fmaf(a0.w, n0, A0.w);
                A1.x = fmaf(b0.x, n0, A1.x);
                A1.y = fmaf(b0.y, n0, A1.y);
                A1.z = fmaf(b0.z, n0, A1.z);
                A1.w = fmaf(b0.w, n0, A1.w);
                A0.x = fmaf(a1.x, n1, A0.x);
                A0.y = fmaf(a1.y, n1, A0.y);
                A0.z = fmaf(a1.z, n1, A0.z);
                A0.w = fmaf(a1.w, n1, A0.w);
                A1.x = fmaf(b1.x, n1, A1.x);
                A1.y = fmaf(b1.y, n1, A1.y);
                A1.z = fmaf(b1.z, n1, A1.z);
                A1.w = fmaf(b1.w, n1, A1.w);
            }
            // tail: 1..7 edges (shfl from lanes >= k yields s=0/ns=0 -> no-op)
            if (kfull < k) {
                int   s0 = __shfl(s,  kfull + q);
                float n0 = __shfl(ns, kfull + q);
                float4 a0, b0;
                ld8(&h[(size_t)s0 * DIM + m * 8], a0, b0);
                if (kfull + 4 < k) {                 // wave-uniform branch
                    int   s1 = __shfl(s,  kfull + 4 + q);
                    float n1 = __shfl(ns, kfull + 4 + q);
                    float4 a1, b1;
                    ld8(&h[(size_t)s1 * DIM + m * 8], a1, b1);
                    A0.x = fmaf(a1.x, n1, A0.x);
                    A0.y = fmaf(a1.y, n1, A0.y);
                    A0.z = fmaf(a1.z, n1, A0.z);
                    A0.w = fmaf(a1.w, n1, A0.w);
                    A1.x = fmaf(b1.x, n1, A1.x);
                    A1.y = fmaf(b1.y, n1, A1.y);
                    A1.z = fmaf(b1.z, n1, A1.z);
                    A1.w = fmaf(b1.w, n1, A1.w);
                }
                A0.x = fmaf(a0.x, n0, A0.x);
                A0.y = fmaf(a0.y, n0, A0.y);
                A0.z = fmaf(a0.z, n0, A0.z);
                A0.w = fmaf(a0.w, n0, A0.w);
                A1.x = fmaf(b0.x, n0, A1.x);
                A1.y = fmaf(b0.y, n0, A1.y);
                A1.z = fmaf(b0.z, n0, A1.z);
                A1.w = fmaf(b0.w, n0, A1.w);
            }
        }
        // cross-quarter reduce: xor 16 then xor 32 -> every lane holds full sum
        A0.x += __shfl_xor(A0.x, 16); A0.y += __shfl_xor(A0.y, 16);
        A0.z += __shfl_xor(A0.z, 16); A0.w += __shfl_xor(A0.w, 16);
        A1.x += __shfl_xor(A1.x, 16); A1.y += __shfl_xor(A1.y, 16);
        A1.z += __shfl_xor(A1.z, 16); A1.w += __shfl_xor(A1.w, 16);
        A0.x += __shfl_xor(A0.x, 32); A0.y += __shfl_xor(A0.y, 32);
        A0.z += __shfl_xor(A0.z, 32); A0.w += __shfl_xor(A0.w, 32);
        A1.x += __shfl_xor(A1.x, 32); A1.y += __shfl_xor(A1.y, 32);
        A1.z += __shfl_xor(A1.z, 32); A1.w += __shfl_xor(A1.w, 32);
        if (q == 0) {
            float4 sa, sb;
            ld8(&h[(size_t)nd * DIM + m * 8], sa, sb);   // self row
            float d2 = dd * dd;
            float4 v0 = make_float4(fmaf(sa.x, d2, A0.x * dd),
                                    fmaf(sa.y, d2, A0.y * dd),
                                    fmaf(sa.z, d2, A0.z * dd),
                                    fmaf(sa.w, d2, A0.w * dd));
            float4 v1 = make_float4(fmaf(sb.x, d2, A1.x * dd),
                                    fmaf(sb.y, d2, A1.y * dd),
                                    fmaf(sb.z, d2, A1.z * dd),
                                    fmaf(sb.w, d2, A1.w * dd));
            *reinterpret_cast<float4*>(&xs[wv * 8 + i][m * 8]) = v0;
            *reinterpret_cast<float4*>(&xs[wv * 8 + i][m * 8 + 4]) = v1;
        }
    }
    __syncthreads();

    // ---- phase 2: GEMM (register-blocked, 4x4 tile/thread) ----
    const int cw = t & 31;                           // cols cw*4..cw*4+3
    const int rb = (t >> 5) * 4;                     // rows rb..rb+3
    const float4* __restrict__ Wv = reinterpret_cast<const float4*>(W);

    float4 acc0 = make_float4(0.f, 0.f, 0.f, 0.f);
    float4 acc1 = acc0, acc2 = acc0, acc3 = acc0;

#pragma unroll 4
    for (int k = 0; k < DIM; ++k) {
        float4 w = Wv[k * 32 + cw];                  // W[k][cw*4..cw*4+3], L1-hot
        float x0 = xs[rb + 0][k];
        float x1 = xs[rb + 1][k];
        float x2 = xs[rb + 2][k];
        float x3 = xs[rb + 3][k];
        acc0.x = fmaf(x0, w.x, acc0.x);
        acc0.y = fmaf(x0, w.y, acc0.y);
        acc0.z = fmaf(x0, w.z, acc0.z);
        acc0.w = fmaf(x0, w.w, acc0.w);
        acc1.x = fmaf(x1, w.x, acc1.x);
        acc1.y = fmaf(x1, w.y, acc1.y);
        acc1.z = fmaf(x1, w.z, acc1.z);
        acc1.w = fmaf(x1, w.w, acc1.w);
        acc2.x = fmaf(x2, w.x, acc2.x);
        acc2.y = fmaf(x2, w.y, acc2.y);
        acc2.z = fmaf(x2, w.z, acc2.z);
        acc2.w = fmaf(x2, w.w, acc2.w);
        acc3.x = fmaf(x3, w.x, acc3.x);
        acc3.y = fmaf(x3, w.y, acc3.y);
        acc3.z = fmaf(x3, w.z, acc3.z);
        acc3.w = fmaf(x3, w.w, acc3.w);
    }

    float4 b4 = *reinterpret_cast<const float4*>(&bias[cw * 4]);
    auto fin = [&](float4 a) {
        a.x += b4.x; a.y += b4.y; a.z += b4.z; a.w += b4.w;
        if (RELU) {
            a.x = fmaxf(a.x, 0.f); a.y = fmaxf(a.y, 0.f);
            a.z = fmaxf(a.z, 0.f); a.w = fmaxf(a.w, 0.f);
        }
        return a;
    };
    size_t o = (size_t)(r0 + rb) * DIM + cw * 4;
    st4(&out[o], fin(acc0));
    st4(&out[o + DIM], fin(acc1));
    st4(&out[o + 2 * DIM], fin(acc2));
    st4(&out[o + 3 * DIM], fin(acc3));
}

// ---------- atomic scatter (fallback for tiny ws) ----------
template <typename ST>
__global__ void scatter_k(const int* __restrict__ src, const int* __restrict__ dst,
                          const float* __restrict__ dinv, const ST* __restrict__ S,
                          float* __restrict__ agg) {
    int i = blockIdx.x * blockDim.x + threadIdx.x;   // grid = NE*32 exactly
    int e = i >> 5;
    int p = (i & 31) * 4;
    int s = src[e], d = dst[e];
    float nrm = dinv[s] * dinv[d];
    float4 hv = ld4(&S[(size_t)s * DIM + p]);
    float* ap = &agg[(size_t)d * DIM + p];
    atomicAdd(ap + 0, hv.x * nrm);
    atomicAdd(ap + 1, hv.y * nrm);
    atomicAdd(ap + 2, hv.z * nrm);
    atomicAdd(ap + 3, hv.w * nrm);
}

// ---------- unfused GEMM (scatter-fallback only) ----------
template <typename ST, typename OT, bool RELU>
__global__ __launch_bounds__(256) void gemm_fused_k(const float* agg, const ST* S,
                                                    const float* __restrict__ dinv,
                                                    const float* __restrict__ W,
                                                    const float* __restrict__ bias,
                                                    OT* out) {
    __shared__ float xs[32][DIM];                    // 16 KB
    const int t = threadIdx.x;
    const int r0 = blockIdx.x * 32;                  // grid = NN/32 exactly

#pragma unroll
    for (int i = 0; i < 4; ++i) {
        int idx = t + i * 256;                       // float4 slot 0..1023
        int rr = idx >> 5;
        int c4 = (idx & 31) * 4;
        int r = r0 + rr;
        float di = dinv[r];
        float d2 = di * di;
        size_t off = (size_t)r * DIM + c4;
        float4 a = *reinterpret_cast<const float4*>(&agg[off]);
        float4 s = ld4(&S[off]);
        xs[rr][c4 + 0] = fmaf(s.x, d2, a.x);
        xs[rr][c4 + 1] = fmaf(s.y, d2, a.y);
        xs[rr][c4 + 2] = fmaf(s.z, d2, a.z);
        xs[rr][c4 + 3] = fmaf(s.w, d2, a.w);
    }
    __syncthreads();

    const int cw = t & 31;
    const int rb = (t >> 5) * 4;
    const float4* __restrict__ Wv = reinterpret_cast<const float4*>(W);

    float4 acc0 = make_float4(0.f, 0.f, 0.f, 0.f);
    float4 acc1 = acc0, acc2 = acc0, acc3 = acc0;

#pragma unroll 4
    for (int k = 0; k < DIM; ++k) {
        float4 w = Wv[k * 32 + cw];
        float x0 = xs[rb + 0][k];
        float x1 = xs[rb + 1][k];
        float x2 = xs[rb + 2][k];
        float x3 = xs[rb + 3][k];
        acc0.x = fmaf(x0, w.x, acc0.x);
        acc0.y = fmaf(x0, w.y, acc0.y);
        acc0.z = fmaf(x0, w.z, acc0.z);
        acc0.w = fmaf(x0, w.w, acc0.w);
        acc1.x = fmaf(x1, w.x, acc1.x);
        acc1.y = fmaf(x1, w.y, acc1.y);
        acc1.z = fmaf(x1, w.z, acc1.z);
        acc1.w = fmaf(x1, w.w, acc1.w);
        acc2.x = fmaf(x2, w.x, acc2.x);
        acc2.y = fmaf(x2, w.y, acc2.y);
        acc2.z = fmaf(x2, w.z, acc2.z);
        acc2.w = fmaf(x2, w.w, acc2.w);
        acc3.x = fmaf(x3, w.x, acc3.x);
        acc3.y = fmaf(x3, w.y, acc3.y);
        acc3.z = fmaf(x3, w.z, acc3.z);
        acc3.w = fmaf(x3, w.w, acc3.w);
    }

    float4 b4 = *reinterpret_cast<const float4*>(&bias[cw * 4]);
    auto fin = [&](float4 a) {
        a.x += b4.x; a.y += b4.y; a.z += b4.z; a.w += b4.w;
        if (RELU) {
            a.x = fmaxf(a.x, 0.f); a.y = fmaxf(a.y, 0.f);
            a.z = fmaxf(a.z, 0.f); a.w = fmaxf(a.w, 0.f);
        }
        return a;
    };
    size_t o = (size_t)(r0 + rb) * DIM + cw * 4;
    st4(&out[o], fin(acc0));
    st4(&out[o + DIM], fin(acc1));
    st4(&out[o + 2 * DIM], fin(acc2));
    st4(&out[o + 3 * DIM], fin(acc3));
}

// ---------- compress / decompress ----------
// 8 elems/thread, float4 in / float4(=4x bf162) out. grid = NB/2048 = 6250.
__global__ void compress8_k(const float* __restrict__ src, bf16* __restrict__ dst) {
    size_t i = (size_t)blockIdx.x * blockDim.x + threadIdx.x;
    const float4* s = reinterpret_cast<const float4*>(src) + i * 2;
    float4 a = s[0], b = s[1];
    bf162 r[4];
    r[0] = __float22bfloat162_rn(make_float2(a.x, a.y));
    r[1] = __float22bfloat162_rn(make_float2(a.z, a.w));
    r[2] = __float22bfloat162_rn(make_float2(b.x, b.y));
    r[3] = __float22bfloat162_rn(make_float2(b.z, b.w));
    *reinterpret_cast<float4*>(dst + i * 8) = *reinterpret_cast<float4*>(r);
}
__global__ void decomp_k(float* __restrict__ dst, const bf16* __restrict__ src, int n) {
    int i = blockIdx.x * blockDim.x + threadIdx.x;
    if (i < n) dst[i] = __bfloat162float(src[i]);
}

// ---------- driver ----------
// ws layout (CSR mode, needs >= 9 MiB):
//   cnt @0 (400KB) | dinv @512K | row_ptr @1M | cursor @1.5M | bsum/boff @2M
//   csr_src @2.25M (6.4MB) | big @9M (graph-1: xb + bf16 H)
// Fallback (ws < 9 MiB): atomic scatter + unfused GEMM, big @1M.
extern "C" void kernel_launch(void* const* d_in, const int* in_sizes, int n_in,
                              void* d_out, int out_size, void* d_ws, size_t ws_size,
                              hipStream_t stream) {
    const float* W0 = (const float*)d_in[4];
    const float* b0 = (const float*)d_in[5];
    const float* W1 = (const float*)d_in[6];
    const float* b1 = (const float*)d_in[7];

    char* ws = (char*)d_ws;
    int*   cnt  = (int*)ws;
    float* dinv = (float*)(ws + (512u << 10));
    int* row_ptr = (int*)(ws + (1u << 20));
    int* cursor  = (int*)(ws + (3u << 19));
    int* bsum    = (int*)(ws + (2u << 20));
    int* boff    = (int*)(ws + (2u << 20) + 4096);
    int* csr_src = (int*)(ws + (9u << 18));          // 2.25 MiB

    const bool csr_ok = ws_size >= (9u << 20);
    char* big = csr_ok ? ws + (9u << 20) : ws + (1u << 20);
    size_t big_avail = ws_size - (csr_ok ? (9u << 20) : (1u << 20));

    const size_t NB = (size_t)NN * DIM;
    float* slot0 = (float*)d_out;
    float* slot1 = slot0 + NB;

    const int SG = (NE * 32) / 256;
    const int GG = NN / 32;                          // 3125
    const int BG = NCHUNK * NSLICE;                  // 1024, sliced build kernels
    const int XG = (int)(NB / 2048);                 // 6250, compress8_k

    auto build = [&](const int* srcp, const int* dstp) {
        hipMemsetAsync(cnt, 0, NN * sizeof(int), stream);
        count_deg_k<<<BG, 256, 0, stream>>>(dstp, cnt);
        dinv_k<<<(NN + 255) / 256, 256, 0, stream>>>(cnt, dinv);
        if (!csr_ok) return;
        blocksum_k<<<NBLK, 256, 0, stream>>>(cnt, bsum);
        scan_bsum_k<<<1, 512, 0, stream>>>(bsum, boff);
        scan_block_k<<<NBLK, 256, 0, stream>>>(cnt, boff, row_ptr, cursor);
        fill_k<<<BG, 256, 0, stream>>>(srcp, dstp, cursor, csr_src);
    };

    if (csr_ok) {
        // ===== graph 0: xb0 (bf16 x) in slot1.hi, h1 bf16 in slot1.lo =====
        // layer1 gathers from xb0 -> writes h1b; layer2 gathers h1b -> slot0.
        {
            const float* x  = (const float*)d_in[0];
            const int*   ei = (const int*)d_in[1];
            bf16* h1b = (bf16*)slot1;                              // 25.6 MB .lo
            bf16* xb0 = (bf16*)((char*)slot1 + NB * sizeof(bf16)); // 25.6 MB .hi
            compress8_k<<<XG, 256, 0, stream>>>(x, xb0);
            build(ei, ei + NE);
            fused_gg_k<bf16, bf16, true><<<GG, 256, 0, stream>>>(
                row_ptr, csr_src, dinv, xb0, W0, b0, h1b);
            fused_gg_k<bf16, float, false><<<GG, 256, 0, stream>>>(
                row_ptr, csr_src, dinv, h1b, W1, b1, slot0);
        }
        // ===== graph 1 =====
        {
            const float* x  = (const float*)d_in[2];
            const int*   ei = (const int*)d_in[3];
            build(ei, ei + NE);

            if (big_avail >= 2 * NB * sizeof(bf16)) {
                // xb + bf16 H both in ws (51.2 MB)
                bf16* xb = (bf16*)big;
                bf16* H  = (bf16*)(big + NB * sizeof(bf16));
                compress8_k<<<XG, 256, 0, stream>>>(x, xb);
                fused_gg_k<bf16, bf16, true><<<GG, 256, 0, stream>>>(
                    row_ptr, csr_src, dinv, xb, W0, b0, H);
                fused_gg_k<bf16, float, false><<<GG, 256, 0, stream>>>(
                    row_ptr, csr_src, dinv, H, W1, b1, slot1);
            } else if (big_avail >= NB * sizeof(bf16)) {
                // bf16 H only; layer1 reads fp32 x directly
                bf16* H = (bf16*)big;
                fused_gg_k<float, bf16, true><<<GG, 256, 0, stream>>>(
                    row_ptr, csr_src, dinv, x, W0, b0, H);
                fused_gg_k<bf16, float, false><<<GG, 256, 0, stream>>>(
                    row_ptr, csr_src, dinv, H, W1, b1, slot1);
            } else {
                // tier 3: stash g0 as bf16 in slot1.lo, h1 bf16 in slot1.hi
                bf16* g0b = (bf16*)slot1;
                bf16* h1b = (bf16*)((char*)slot1 + NB * sizeof(bf16));
                compress8_k<<<XG, 256, 0, stream>>>(slot0, g0b);
                fused_gg_k<float, bf16, true><<<GG, 256, 0, stream>>>(
                    row_ptr, csr_src, dinv, x, W0, b0, h1b);
                fused_gg_k<bf16, float, false><<<GG, 256, 0, stream>>>(
                    row_ptr, csr_src, dinv, h1b, W1, b1, slot0);
                // swap: slot0 (g1) -> slot1, decompress g0b -> slot0.
                float* stage = (float*)csr_src;      // CSR dead now
                size_t C = 1600000;
                size_t a = NB;
                while (a > 0) {
                    size_t len = (a >= C) ? C : a;
                    a -= len;
                    hipMemcpyAsync(stage, slot0 + a, len * sizeof(float),
                                   hipMemcpyDeviceToDevice, stream);
                    decomp_k<<<(int)((len + 255) / 256), 256, 0, stream>>>(
                        slot0 + a, g0b + a, (int)len);
                    hipMemcpyAsync(slot1 + a, stage, len * sizeof(float),
                                   hipMemcpyDeviceToDevice, stream);
                }
            }
        }
        return;
    }

    // ================= fallback: atomic scatter + unfused GEMM =================
    auto agg_f = [&](const int* srcp, const int* dstp, const float* h, float* agg) {
        hipMemsetAsync(agg, 0, NB * sizeof(float), stream);
        scatter_k<float><<<SG, 256, 0, stream>>>(srcp, dstp, dinv, h, agg);
    };
    auto agg_b = [&](const int* srcp, const int* dstp, const bf16* h, float* agg) {
        hipMemsetAsync(agg, 0, NB * sizeof(float), stream);
        scatter_k<bf16><<<SG, 256, 0, stream>>>(srcp, dstp, dinv, h, agg);
    };

    // graph 0
    {
        const float* x  = (const float*)d_in[0];
        const int*   ei = (const int*)d_in[1];
        bf16* h1b = (bf16*)slot1;
        build(ei, ei + NE);
        agg_f(ei, ei + NE, x, slot0);
        gemm_fused_k<float, bf16, true><<<GG, 256, 0, stream>>>(slot0, x, dinv, W0, b0, h1b);
        agg_b(ei, ei + NE, h1b, slot0);
        gemm_fused_k<bf16, float, false><<<GG, 256, 0, stream>>>(slot0, h1b, dinv, W1, b1, slot0);
    }
    // graph 1
    {
        const float* x  = (const float*)d_in[2];
        const int*   ei = (const int*)d_in[3];
        build(ei, ei + NE);

        // tier 3 (ws < 9 MiB cannot hold bf16 H of 25.6 MB either)
        bf16* g0b = (bf16*)slot1;
        bf16* h1b = (bf16*)((char*)slot1 + NB * sizeof(bf16));
        compress8_k<<<XG, 256, 0, stream>>>(slot0, g0b);
        agg_f(ei, ei + NE, x, slot0);
        gemm_fused_k<float, bf16, true><<<GG, 256, 0, stream>>>(slot0, x, dinv, W0, b0, h1b);
        agg_b(ei, ei + NE, h1b, slot0);
        gemm_fused_k<bf16, float, false><<<GG, 256, 0, stream>>>(slot0, h1b, dinv, W1, b1, slot0);
        float* stage = (float*)big;
        size_t C = (big_avail / sizeof(float)) & ~(size_t)255;
        if (C < 256) C = 256;
        size_t a = NB;
        while (a > 0) {
            size_t len = (a >= C) ? C : a;
            a -= len;
            hipMemcpyAsync(stage, slot0 + a, len * sizeof(float),
                           hipMemcpyDeviceToDevice, stream);
            decomp_k<<<(int)((len + 255) / 256), 256, 0, stream>>>(
                slot0 + a, g0b + a, (int)len);
            hipMemcpyAsync(slot1 + a, stage, len * sizeof(float),
                           hipMemcpyDeviceToDevice, stream);
        }
    }
}

// Round 8
// 792.889 us; speedup vs baseline: 1.9770x; 1.1937x over previous
//
#include <hip/hip_runtime.h>
#include <hip/hip_bf16.h>

#define NN 100000
#define NE 1600000
#define DIM 128
#define NBLK ((NN + 255) / 256)   // 391

// XCD-sliced CSR build: 8 dst-slices of 12500 nodes, 128 edge-chunks of 12500
#define NSLICE 8
#define SLICE_N 12500             // NN / 8
#define NCHUNK 128
#define CHUNK_E 12500             // NE / 128

using bf16 = __hip_bfloat16;
using bf162 = __hip_bfloat162;
typedef __attribute__((ext_vector_type(8))) short short8v;   // bf16x8 MFMA frag
typedef __attribute__((ext_vector_type(4))) float f32x4;     // MFMA accumulator

// ---------- dtype helpers ----------
__device__ __forceinline__ float to_f(const float v) { return v; }
__device__ __forceinline__ float to_f(const bf16 v) { return __bfloat162float(v); }

__device__ __forceinline__ float4 ld4(const float* p) {
    return *reinterpret_cast<const float4*>(p);
}
__device__ __forceinline__ float4 ld4(const bf16* p) {
    const bf162* q = reinterpret_cast<const bf162*>(p);
    float2 a = __bfloat1622float2(q[0]);
    float2 b = __bfloat1622float2(q[1]);
    return make_float4(a.x, a.y, b.x, b.y);
}
// 8 consecutive elements -> two float4 (a: cols+0..3, b: cols+4..7)
__device__ __forceinline__ void ld8(const float* p, float4& a, float4& b) {
    a = *reinterpret_cast<const float4*>(p);
    b = *reinterpret_cast<const float4*>(p + 4);
}
__device__ __forceinline__ void ld8(const bf16* p, float4& a, float4& b) {
    float4 r = *reinterpret_cast<const float4*>(p);   // 8 bf16 in one 16B load
    const bf162* q = reinterpret_cast<const bf162*>(&r);
    float2 f0 = __bfloat1622float2(q[0]);
    float2 f1 = __bfloat1622float2(q[1]);
    float2 f2 = __bfloat1622float2(q[2]);
    float2 f3 = __bfloat1622float2(q[3]);
    a = make_float4(f0.x, f0.y, f1.x, f1.y);
    b = make_float4(f2.x, f2.y, f3.x, f3.y);
}
__device__ __forceinline__ void st1(float* p, float v) { *p = v; }
__device__ __forceinline__ void st1(bf16* p, float v) { *p = __float2bfloat16(v); }
__device__ __forceinline__ void st4(float* p, float4 v) {
    *reinterpret_cast<float4*>(p) = v;
}
__device__ __forceinline__ void st4(bf16* p, float4 v) {
    bf162* q = reinterpret_cast<bf162*>(p);
    q[0] = __float22bfloat162_rn(make_float2(v.x, v.y));
    q[1] = __float22bfloat162_rn(make_float2(v.z, v.w));
}
// pack 8 fp32 -> 16B of bf16
__device__ __forceinline__ float4 pack8(float4 a, float4 b) {
    bf162 r[4];
    r[0] = __float22bfloat162_rn(make_float2(a.x, a.y));
    r[1] = __float22bfloat162_rn(make_float2(a.z, a.w));
    r[2] = __float22bfloat162_rn(make_float2(b.x, b.y));
    r[3] = __float22bfloat162_rn(make_float2(b.z, b.w));
    return *reinterpret_cast<float4*>(r);
}

// ---------- degree / normalization ----------
// XCD-sliced: blockIdx&7 selects a dst-slice (lands on one XCD under
// round-robin dispatch) -> atomic working set per XCD is L2-local.
__global__ __launch_bounds__(256) void count_deg_k(const int* __restrict__ dst,
                                                   int* __restrict__ cnt) {
    const int s = blockIdx.x & 7;
    const int c = blockIdx.x >> 3;                   // grid = NCHUNK*8
    const int lo = s * SLICE_N;
    const int beg = c * CHUNK_E, end = beg + CHUNK_E;
    for (int e = beg + threadIdx.x; e < end; e += 256) {
        int d = dst[e];
        if ((unsigned)(d - lo) < (unsigned)SLICE_N) atomicAdd(&cnt[d], 1);
    }
}

__global__ void dinv_k(const int* __restrict__ cnt, float* __restrict__ dinv) {
    int i = blockIdx.x * blockDim.x + threadIdx.x;
    if (i < NN) dinv[i] = rsqrtf((float)cnt[i] + 1.0f);   // +1 self-loop
}

// ---------- CSR build: two-level exclusive scan + cursor fill ----------
__global__ void blocksum_k(const int* __restrict__ cnt, int* __restrict__ bsum) {
    __shared__ int s[256];
    int i = blockIdx.x * 256 + threadIdx.x;
    s[threadIdx.x] = (i < NN) ? cnt[i] : 0;
    __syncthreads();
    for (int off = 128; off > 0; off >>= 1) {
        if (threadIdx.x < off) s[threadIdx.x] += s[threadIdx.x + off];
        __syncthreads();
    }
    if (threadIdx.x == 0) bsum[blockIdx.x] = s[0];
}

__global__ void scan_bsum_k(const int* __restrict__ bsum, int* __restrict__ boff) {
    __shared__ int s[512];                           // 1 block of 512 covers NBLK=391
    int t = threadIdx.x;
    int v = (t < NBLK) ? bsum[t] : 0;
    s[t] = v;
    __syncthreads();
    for (int off = 1; off < 512; off <<= 1) {
        int tmp = (t >= off) ? s[t - off] : 0;
        __syncthreads();
        s[t] += tmp;
        __syncthreads();
    }
    if (t < NBLK) boff[t] = s[t] - v;                // exclusive
}

// also emits dinv (CSR path; saves the separate dinv_k dispatch)
__global__ void scan_block_k(const int* __restrict__ cnt, const int* __restrict__ boff,
                             int* __restrict__ row_ptr, int* __restrict__ cursor,
                             float* __restrict__ dinv) {
    __shared__ int s[256];
    int t = threadIdx.x, i = blockIdx.x * 256 + t;
    int v = (i < NN) ? cnt[i] : 0;
    s[t] = v;
    __syncthreads();
    for (int off = 1; off < 256; off <<= 1) {
        int tmp = (t >= off) ? s[t - off] : 0;
        __syncthreads();
        s[t] += tmp;
        __syncthreads();
    }
    if (i < NN) {
        int e = boff[blockIdx.x] + s[t] - v;         // global exclusive
        row_ptr[i] = e;
        cursor[i] = e;
        dinv[i] = rsqrtf((float)v + 1.0f);           // +1 self-loop
    }
    if (i == NN - 1) row_ptr[NN] = NE;
}

// XCD-sliced cursor fill (same slicing as count_deg_k): per-slice csr_src
// region is ~0.8 MB -> one XCD's L2, write amplification ~1.
__global__ __launch_bounds__(256) void fill_k(const int* __restrict__ src,
                                              const int* __restrict__ dst,
                                              int* __restrict__ cursor,
                                              int* __restrict__ csr_src) {
    const int s = blockIdx.x & 7;
    const int c = blockIdx.x >> 3;                   // grid = NCHUNK*8
    const int lo = s * SLICE_N;
    const int beg = c * CHUNK_E, end = beg + CHUNK_E;
    for (int e = beg + threadIdx.x; e < end; e += 256) {
        int d = dst[e];
        if ((unsigned)(d - lo) < (unsigned)SLICE_N) {
            int pos = atomicAdd(&cursor[d], 1);
            csr_src[pos] = src[e];
        }
    }
}

// ---------- W -> fragment-ordered bf16 (one-time) ----------
// Wb[(ct*4+ks)*64 + lane][j] = bf16( W[(ks*32 + (lane>>4)*8 + j)*128 + ct*16 + (lane&15)] )
// Any consistent k-permutation in (lane>>4, j) cancels between A and B loads.
__global__ void wcvt_k(const float* __restrict__ W0, const float* __restrict__ W1,
                       bf16* __restrict__ Wb0, bf16* __restrict__ Wb1) {
    int idx = blockIdx.x * 256 + threadIdx.x;        // grid = 128 -> 32768
    const float* W = (idx & 16384) ? W1 : W0;
    bf16* Wb = (idx & 16384) ? Wb1 : Wb0;
    int e = idx & 16383;
    int j = e & 7, l = (e >> 3) & 63, ks = (e >> 9) & 3, ct = e >> 11;
    int k = ks * 32 + (l >> 4) * 8 + j;
    int c = ct * 16 + (l & 15);
    Wb[e] = __float2bfloat16(W[k * 128 + c]);
}

// ---------- FUSED gather + MFMA GEMM ----------
// out[r] = act( (dd*sum_{s in N(r)} dinv[s]*h[s] + dd^2*h[r]) @ W + b )
// Block = 32 nodes (grid NN/32). Phase 1: 4 quarter-waves, 8 edges/iter, bf16
// table (fabric random-read floor: 8 XCD x 25.6 MB = ~198 MB FETCH). Rows land
// in LDS as bf16 with 16B-unit XOR swizzle (unit ^= row&7): conflict-free
// stores AND conflict-free MFMA A-fragment b128 reads (row-major stride-256B
// would be 16-way, Guideline 4). Phase 2: mfma_f32_16x16x32_bf16, B-fragments
// from fragment-ordered global Wb (L1-hot 16B loads). ~120 wave-instr vs 2688
// scalar (VALUBusy 43% was the round-7 limiter).
template <typename ST, typename OT, bool RELU>
__global__ __launch_bounds__(256) void fused_gg_k(const int* __restrict__ row_ptr,
                                                  const int* __restrict__ csr_src,
                                                  const float* __restrict__ dinv,
                                                  const ST* __restrict__ h,
                                                  const bf16* __restrict__ Wb,
                                                  const float* __restrict__ bias,
                                                  OT* __restrict__ out) {
    __shared__ __align__(16) bf16 xs[32][DIM];       // 8 KB, swizzled 16B units
    const int t = threadIdx.x;
    const int r0 = blockIdx.x * 32;                  // grid = NN/32 exactly
    const int wv = t >> 6;                           // wave 0..3
    const int lane = t & 63;
    const int q = lane >> 4;                         // edge slot 0..3
    const int m = lane & 15;                         // col octet: cols m*8..m*8+7

    // ---- phase 1: gather 8 nodes per wave ----
    for (int i = 0; i < 8; ++i) {
        const int nd = r0 + wv * 8 + i;
        const int beg = row_ptr[nd], end = row_ptr[nd + 1];
        const float dd = dinv[nd];
        float4 A0 = make_float4(0.f, 0.f, 0.f, 0.f);
        float4 A1 = A0;
        for (int base = beg; base < end; base += 64) {
            int k = end - base;
            if (k > 64) k = 64;
            int s = 0;
            float ns = 0.f;
            if (lane < k) { s = csr_src[base + lane]; ns = dinv[s]; }
            const int kfull = k & ~7;
            // hot path: 8 edges per iteration
            for (int j = 0; j < kfull; j += 8) {
                int   s0 = __shfl(s,  j + q);
                float n0 = __shfl(ns, j + q);
                int   s1 = __shfl(s,  j + 4 + q);
                float n1 = __shfl(ns, j + 4 + q);
                float4 a0, b0, a1, b1;
                ld8(&h[(size_t)s0 * DIM + m * 8], a0, b0);
                ld8(&h[(size_t)s1 * DIM + m * 8], a1, b1);
                A0.x = fmaf(a0.x, n0, A0.x);
                A0.y = fmaf(a0.y, n0, A0.y);
                A0.z = fmaf(a0.z, n0, A0.z);
                A0.w = fmaf(a0.w, n0, A0.w);
                A1.x = fmaf(b0.x, n0, A1.x);
                A1.y = fmaf(b0.y, n0, A1.y);
                A1.z = fmaf(b0.z, n0, A1.z);
                A1.w = fmaf(b0.w, n0, A1.w);
                A0.x = fmaf(a1.x, n1, A0.x);
                A0.y = fmaf(a1.y, n1, A0.y);
                A0.z = fmaf(a1.z, n1, A0.z);
                A0.w = fmaf(a1.w, n1, A0.w);
                A1.x = fmaf(b1.x, n1, A1.x);
                A1.y = fmaf(b1.y, n1, A1.y);
                A1.z = fmaf(b1.z, n1, A1.z);
                A1.w = fmaf(b1.w, n1, A1.w);
            }
            // tail: 1..7 edges (shfl from lanes >= k yields s=0/ns=0 -> no-op)
            if (kfull < k) {
                int   s0 = __shfl(s,  kfull + q);
                float n0 = __shfl(ns, kfull + q);
                float4 a0, b0;
                ld8(&h[(size_t)s0 * DIM + m * 8], a0, b0);
                if (kfull + 4 < k) {                 // wave-uniform branch
                    int   s1 = __shfl(s,  kfull + 4 + q);
                    float n1 = __shfl(ns, kfull + 4 + q);
                    float4 a1, b1;
                    ld8(&h[(size_t)s1 * DIM + m * 8], a1, b1);
                    A0.x = fmaf(a1.x, n1, A0.x);
                    A0.y = fmaf(a1.y, n1, A0.y);
                    A0.z = fmaf(a1.z, n1, A0.z);
                    A0.w = fmaf(a1.w, n1, A0.w);
                    A1.x = fmaf(b1.x, n1, A1.x);
                    A1.y = fmaf(b1.y, n1, A1.y);
                    A1.z = fmaf(b1.z, n1, A1.z);
                    A1.w = fmaf(b1.w, n1, A1.w);
                }
                A0.x = fmaf(a0.x, n0, A0.x);
                A0.y = fmaf(a0.y, n0, A0.y);
                A0.z = fmaf(a0.z, n0, A0.z);
                A0.w = fmaf(a0.w, n0, A0.w);
                A1.x = fmaf(b0.x, n0, A1.x);
                A1.y = fmaf(b0.y, n0, A1.y);
                A1.z = fmaf(b0.z, n0, A1.z);
                A1.w = fmaf(b0.w, n0, A1.w);
            }
        }
        // cross-quarter reduce: xor 16 then xor 32 -> every lane holds full sum
        A0.x += __shfl_xor(A0.x, 16); A0.y += __shfl_xor(A0.y, 16);
        A0.z += __shfl_xor(A0.z, 16); A0.w += __shfl_xor(A0.w, 16);
        A1.x += __shfl_xor(A1.x, 16); A1.y += __shfl_xor(A1.y, 16);
        A1.z += __shfl_xor(A1.z, 16); A1.w += __shfl_xor(A1.w, 16);
        A0.x += __shfl_xor(A0.x, 32); A0.y += __shfl_xor(A0.y, 32);
        A0.z += __shfl_xor(A0.z, 32); A0.w += __shfl_xor(A0.w, 32);
        A1.x += __shfl_xor(A1.x, 32); A1.y += __shfl_xor(A1.y, 32);
        A1.z += __shfl_xor(A1.z, 32); A1.w += __shfl_xor(A1.w, 32);
        if (q == 0) {
            float4 sa, sb;
            ld8(&h[(size_t)nd * DIM + m * 8], sa, sb);   // self row
            const int row = wv * 8 + i;
            float d2 = dd * dd;
            float4 v0 = make_float4(fmaf(sa.x, d2, A0.x * dd),
                                    fmaf(sa.y, d2, A0.y * dd),
                                    fmaf(sa.z, d2, A0.z * dd),
                                    fmaf(sa.w, d2, A0.w * dd));
            float4 v1 = make_float4(fmaf(sb.x, d2, A1.x * dd),
                                    fmaf(sb.y, d2, A1.y * dd),
                                    fmaf(sb.z, d2, A1.z * dd),
                                    fmaf(sb.w, d2, A1.w * dd));
            // swizzled 16B-unit store: unit m -> m ^ (row&7); 16 lanes cover a
            // permutation of the row's 16 units -> 2-way banks (free)
            *reinterpret_cast<float4*>(&xs[row][(m ^ (row & 7)) * 8]) = pack8(v0, v1);
        }
    }
    __syncthreads();

    // ---- phase 2: MFMA GEMM (32x128 @ 128x128) ----
    // wave wv owns cols wv*32..wv*32+31 (col-tiles 2wv, 2wv+1) x all 32 rows.
    const int g  = lane >> 4;                        // k-group 0..3
    const int cl = lane & 15;                        // A-row / B-col within tile
    const short8v* __restrict__ Wb8 = reinterpret_cast<const short8v*>(Wb);
    f32x4 acc00 = {0.f, 0.f, 0.f, 0.f};
    f32x4 acc01 = acc00, acc10 = acc00, acc11 = acc00;
    const int ct0 = wv * 2, ct1 = wv * 2 + 1;
#pragma unroll
    for (int ks = 0; ks < 4; ++ks) {
        const int u = (ks * 4 + g) ^ (cl & 7);       // swizzled 16B unit
        short8v a0 = *reinterpret_cast<const short8v*>(&xs[cl][u * 8]);
        short8v a1 = *reinterpret_cast<const short8v*>(&xs[16 + cl][u * 8]);
        short8v b0 = Wb8[(ct0 * 4 + ks) * 64 + lane];
        short8v b1 = Wb8[(ct1 * 4 + ks) * 64 + lane];
        acc00 = __builtin_amdgcn_mfma_f32_16x16x32_bf16(a0, b0, acc00, 0, 0, 0);
        acc01 = __builtin_amdgcn_mfma_f32_16x16x32_bf16(a0, b1, acc01, 0, 0, 0);
        acc10 = __builtin_amdgcn_mfma_f32_16x16x32_bf16(a1, b0, acc10, 0, 0, 0);
        acc11 = __builtin_amdgcn_mfma_f32_16x16x32_bf16(a1, b1, acc11, 0, 0, 0);
    }
    // C/D: col = lane&15, row = (lane>>4)*4 + reg  [HW-verified mapping]
    const int colb = wv * 32 + cl;
    const float bb0 = bias[colb];
    const float bb1 = bias[colb + 16];
#pragma unroll
    for (int r = 0; r < 4; ++r) {
        int row_a = r0 + g * 4 + r;                  // rt = 0
        int row_b = r0 + 16 + g * 4 + r;             // rt = 1
        float v00 = acc00[r] + bb0, v01 = acc01[r] + bb1;
        float v10 = acc10[r] + bb0, v11 = acc11[r] + bb1;
        if (RELU) {
            v00 = fmaxf(v00, 0.f); v01 = fmaxf(v01, 0.f);
            v10 = fmaxf(v10, 0.f); v11 = fmaxf(v11, 0.f);
        }
        st1(&out[(size_t)row_a * DIM + colb], v00);
        st1(&out[(size_t)row_a * DIM + colb + 16], v01);
        st1(&out[(size_t)row_b * DIM + colb], v10);
        st1(&out[(size_t)row_b * DIM + colb + 16], v11);
    }
}

// ---------- atomic scatter (fallback for tiny ws) ----------
template <typename ST>
__global__ void scatter_k(const int* __restrict__ src, const int* __restrict__ dst,
                          const float* __restrict__ dinv, const ST* __restrict__ S,
                          float* __restrict__ agg) {
    int i = blockIdx.x * blockDim.x + threadIdx.x;   // grid = NE*32 exactly
    int e = i >> 5;
    int p = (i & 31) * 4;
    int s = src[e], d = dst[e];
    float nrm = dinv[s] * dinv[d];
    float4 hv = ld4(&S[(size_t)s * DIM + p]);
    float* ap = &agg[(size_t)d * DIM + p];
    atomicAdd(ap + 0, hv.x * nrm);
    atomicAdd(ap + 1, hv.y * nrm);
    atomicAdd(ap + 2, hv.z * nrm);
    atomicAdd(ap + 3, hv.w * nrm);
}

// ---------- unfused GEMM (scatter-fallback only; fp32 W) ----------
template <typename ST, typename OT, bool RELU>
__global__ __launch_bounds__(256) void gemm_fused_k(const float* agg, const ST* S,
                                                    const float* __restrict__ dinv,
                                                    const float* __restrict__ W,
                                                    const float* __restrict__ bias,
                                                    OT* out) {
    __shared__ float xs[32][DIM];                    // 16 KB
    const int t = threadIdx.x;
    const int r0 = blockIdx.x * 32;                  // grid = NN/32 exactly

#pragma unroll
    for (int i = 0; i < 4; ++i) {
        int idx = t + i * 256;                       // float4 slot 0..1023
        int rr = idx >> 5;
        int c4 = (idx & 31) * 4;
        int r = r0 + rr;
        float di = dinv[r];
        float d2 = di * di;
        size_t off = (size_t)r * DIM + c4;
        float4 a = *reinterpret_cast<const float4*>(&agg[off]);
        float4 s = ld4(&S[off]);
        xs[rr][c4 + 0] = fmaf(s.x, d2, a.x);
        xs[rr][c4 + 1] = fmaf(s.y, d2, a.y);
        xs[rr][c4 + 2] = fmaf(s.z, d2, a.z);
        xs[rr][c4 + 3] = fmaf(s.w, d2, a.w);
    }
    __syncthreads();

    const int cw = t & 31;
    const int rb = (t >> 5) * 4;
    const float4* __restrict__ Wv = reinterpret_cast<const float4*>(W);

    float4 acc0 = make_float4(0.f, 0.f, 0.f, 0.f);
    float4 acc1 = acc0, acc2 = acc0, acc3 = acc0;

#pragma unroll 4
    for (int k = 0; k < DIM; ++k) {
        float4 w = Wv[k * 32 + cw];
        float x0 = xs[rb + 0][k];
        float x1 = xs[rb + 1][k];
        float x2 = xs[rb + 2][k];
        float x3 = xs[rb + 3][k];
        acc0.x = fmaf(x0, w.x, acc0.x);
        acc0.y = fmaf(x0, w.y, acc0.y);
        acc0.z = fmaf(x0, w.z, acc0.z);
        acc0.w = fmaf(x0, w.w, acc0.w);
        acc1.x = fmaf(x1, w.x, acc1.x);
        acc1.y = fmaf(x1, w.y, acc1.y);
        acc1.z = fmaf(x1, w.z, acc1.z);
        acc1.w = fmaf(x1, w.w, acc1.w);
        acc2.x = fmaf(x2, w.x, acc2.x);
        acc2.y = fmaf(x2, w.y, acc2.y);
        acc2.z = fmaf(x2, w.z, acc2.z);
        acc2.w = fmaf(x2, w.w, acc2.w);
        acc3.x = fmaf(x3, w.x, acc3.x);
        acc3.y = fmaf(x3, w.y, acc3.y);
        acc3.z = fmaf(x3, w.z, acc3.z);
        acc3.w = fmaf(x3, w.w, acc3.w);
    }

    float4 b4 = *reinterpret_cast<const float4*>(&bias[cw * 4]);
    auto fin = [&](float4 a) {
        a.x += b4.x; a.y += b4.y; a.z += b4.z; a.w += b4.w;
        if (RELU) {
            a.x = fmaxf(a.x, 0.f); a.y = fmaxf(a.y, 0.f);
            a.z = fmaxf(a.z, 0.f); a.w = fmaxf(a.w, 0.f);
        }
        return a;
    };
    size_t o = (size_t)(r0 + rb) * DIM + cw * 4;
    st4(&out[o], fin(acc0));
    st4(&out[o + DIM], fin(acc1));
    st4(&out[o + 2 * DIM], fin(acc2));
    st4(&out[o + 3 * DIM], fin(acc3));
}

// ---------- compress / decompress ----------
// 8 elems/thread, float4 in / float4(=4x bf162) out. grid = NB/2048 = 6250.
__global__ void compress8_k(const float* __restrict__ src, bf16* __restrict__ dst) {
    size_t i = (size_t)blockIdx.x * blockDim.x + threadIdx.x;
    const float4* s = reinterpret_cast<const float4*>(src) + i * 2;
    float4 a = s[0], b = s[1];
    *reinterpret_cast<float4*>(dst + i * 8) = pack8(a, b);
}
__global__ void decomp_k(float* __restrict__ dst, const bf16* __restrict__ src, int n) {
    int i = blockIdx.x * blockDim.x + threadIdx.x;
    if (i < n) dst[i] = __bfloat162float(src[i]);
}

// ---------- driver ----------
// ws layout (CSR mode, needs >= 9 MiB):
//   cnt @0 (400KB) | dinv @512K | row_ptr @1M | cursor @1.5M
//   bsum @2M | boff @2M+4K | Wb0 @2M+8K (32KB) | Wb1 @2M+40K (32KB)
//   csr_src @2.25M (6.4MB) | big @9M (graph-1: xb + bf16 H)
// Fallback (ws < 9 MiB): atomic scatter + unfused fp32 GEMM, big @1M.
extern "C" void kernel_launch(void* const* d_in, const int* in_sizes, int n_in,
                              void* d_out, int out_size, void* d_ws, size_t ws_size,
                              hipStream_t stream) {
    const float* W0 = (const float*)d_in[4];
    const float* b0 = (const float*)d_in[5];
    const float* W1 = (const float*)d_in[6];
    const float* b1 = (const float*)d_in[7];

    char* ws = (char*)d_ws;
    int*   cnt  = (int*)ws;
    float* dinv = (float*)(ws + (512u << 10));
    int* row_ptr = (int*)(ws + (1u << 20));
    int* cursor  = (int*)(ws + (3u << 19));
    int* bsum    = (int*)(ws + (2u << 20));
    int* boff    = (int*)(ws + (2u << 20) + 4096);
    bf16* Wb0    = (bf16*)(ws + (2u << 20) + 8192);
    bf16* Wb1    = Wb0 + 16384;
    int* csr_src = (int*)(ws + (9u << 18));          // 2.25 MiB

    const bool csr_ok = ws_size >= (9u << 20);
    char* big = csr_ok ? ws + (9u << 20) : ws + (1u << 20);
    size_t big_avail = ws_size - (csr_ok ? (9u << 20) : (1u << 20));

    const size_t NB = (size_t)NN * DIM;
    float* slot0 = (float*)d_out;
    float* slot1 = slot0 + NB;

    const int SG = (NE * 32) / 256;
    const int GG = NN / 32;                          // 3125
    const int BG = NCHUNK * NSLICE;                  // 1024, sliced build kernels
    const int XG = (int)(NB / 2048);                 // 6250, compress8_k

    auto build = [&](const int* srcp, const int* dstp) {
        hipMemsetAsync(cnt, 0, NN * sizeof(int), stream);
        count_deg_k<<<BG, 256, 0, stream>>>(dstp, cnt);
        if (!csr_ok) {
            dinv_k<<<(NN + 255) / 256, 256, 0, stream>>>(cnt, dinv);
            return;
        }
        blocksum_k<<<NBLK, 256, 0, stream>>>(cnt, bsum);
        scan_bsum_k<<<1, 512, 0, stream>>>(bsum, boff);
        scan_block_k<<<NBLK, 256, 0, stream>>>(cnt, boff, row_ptr, cursor, dinv);
        fill_k<<<BG, 256, 0, stream>>>(srcp, dstp, cursor, csr_src);
    };

    if (csr_ok) {
        wcvt_k<<<128, 256, 0, stream>>>(W0, W1, Wb0, Wb1);
        // ===== graph 0: xb0 (bf16 x) in slot1.hi, h1 bf16 in slot1.lo =====
        {
            const float* x  = (const float*)d_in[0];
            const int*   ei = (const int*)d_in[1];
            bf16* h1b = (bf16*)slot1;                              // 25.6 MB .lo
            bf16* xb0 = (bf16*)((char*)slot1 + NB * sizeof(bf16)); // 25.6 MB .hi
            compress8_k<<<XG, 256, 0, stream>>>(x, xb0);
            build(ei, ei + NE);
            fused_gg_k<bf16, bf16, true><<<GG, 256, 0, stream>>>(
                row_ptr, csr_src, dinv, xb0, Wb0, b0, h1b);
            fused_gg_k<bf16, float, false><<<GG, 256, 0, stream>>>(
                row_ptr, csr_src, dinv, h1b, Wb1, b1, slot0);
        }
        // ===== graph 1 =====
        {
            const float* x  = (const float*)d_in[2];
            const int*   ei = (const int*)d_in[3];
            build(ei, ei + NE);

            if (big_avail >= 2 * NB * sizeof(bf16)) {
                // xb + bf16 H both in ws (51.2 MB)
                bf16* xb = (bf16*)big;
                bf16* H  = (bf16*)(big + NB * sizeof(bf16));
                compress8_k<<<XG, 256, 0, stream>>>(x, xb);
                fused_gg_k<bf16, bf16, true><<<GG, 256, 0, stream>>>(
                    row_ptr, csr_src, dinv, xb, Wb0, b0, H);
                fused_gg_k<bf16, float, false><<<GG, 256, 0, stream>>>(
                    row_ptr, csr_src, dinv, H, Wb1, b1, slot1);
            } else if (big_avail >= NB * sizeof(bf16)) {
                // bf16 H only; layer1 reads fp32 x directly
                bf16* H = (bf16*)big;
                fused_gg_k<float, bf16, true><<<GG, 256, 0, stream>>>(
                    row_ptr, csr_src, dinv, x, Wb0, b0, H);
                fused_gg_k<bf16, float, false><<<GG, 256, 0, stream>>>(
                    row_ptr, csr_src, dinv, H, Wb1, b1, slot1);
            } else {
                // tier 3: stash g0 as bf16 in slot1.lo, h1 bf16 in slot1.hi
                bf16* g0b = (bf16*)slot1;
                bf16* h1b = (bf16*)((char*)slot1 + NB * sizeof(bf16));
                compress8_k<<<XG, 256, 0, stream>>>(slot0, g0b);
                fused_gg_k<float, bf16, true><<<GG, 256, 0, stream>>>(
                    row_ptr, csr_src, dinv, x, Wb0, b0, h1b);
                fused_gg_k<bf16, float, false><<<GG, 256, 0, stream>>>(
                    row_ptr, csr_src, dinv, h1b, Wb1, b1, slot0);
                // swap: slot0 (g1) -> slot1, decompress g0b -> slot0.
                float* stage = (float*)csr_src;      // CSR dead now
                size_t C = 1600000;
                size_t a = NB;
                while (a > 0) {
                    size_t len = (a >= C) ? C : a;
                    a -= len;
                    hipMemcpyAsync(stage, slot0 + a, len * sizeof(float),
                                   hipMemcpyDeviceToDevice, stream);
                    decomp_k<<<(int)((len + 255) / 256), 256, 0, stream>>>(
                        slot0 + a, g0b + a, (int)len);
                    hipMemcpyAsync(slot1 + a, stage, len * sizeof(float),
                                   hipMemcpyDeviceToDevice, stream);
                }
            }
        }
        return;
    }

    // ================= fallback: atomic scatter + unfused GEMM =================
    auto agg_f = [&](const int* srcp, const int* dstp, const float* h, float* agg) {
        hipMemsetAsync(agg, 0, NB * sizeof(float), stream);
        scatter_k<float><<<SG, 256, 0, stream>>>(srcp, dstp, dinv, h, agg);
    };
    auto agg_b = [&](const int* srcp, const int* dstp, const bf16* h, float* agg) {
        hipMemsetAsync(agg, 0, NB * sizeof(float), stream);
        scatter_k<bf16><<<SG, 256, 0, stream>>>(srcp, dstp, dinv, h, agg);
    };

    // graph 0
    {
        const float* x  = (const float*)d_in[0];
        const int*   ei = (const int*)d_in[1];
        bf16* h1b = (bf16*)slot1;
        build(ei, ei + NE);
        agg_f(ei, ei + NE, x, slot0);
        gemm_fused_k<float, bf16, true><<<GG, 256, 0, stream>>>(slot0, x, dinv, W0, b0, h1b);
        agg_b(ei, ei + NE, h1b, slot0);
        gemm_fused_k<bf16, float, false><<<GG, 256, 0, stream>>>(slot0, h1b, dinv, W1, b1, slot0);
    }
    // graph 1
    {
        const float* x  = (const float*)d_in[2];
        const int*   ei = (const int*)d_in[3];
        build(ei, ei + NE);

        // tier 3 (ws < 9 MiB cannot hold bf16 H of 25.6 MB either)
        bf16* g0b = (bf16*)slot1;
        bf16* h1b = (bf16*)((char*)slot1 + NB * sizeof(bf16));
        compress8_k<<<XG, 256, 0, stream>>>(slot0, g0b);
        agg_f(ei, ei + NE, x, slot0);
        gemm_fused_k<float, bf16, true><<<GG, 256, 0, stream>>>(slot0, x, dinv, W0, b0, h1b);
        agg_b(ei, ei + NE, h1b, slot0);
        gemm_fused_k<bf16, float, false><<<GG, 256, 0, stream>>>(slot0, h1b, dinv, W1, b1, slot0);
        float* stage = (float*)big;
        size_t C = (big_avail / sizeof(float)) & ~(size_t)255;
        if (C < 256) C = 256;
        size_t a = NB;
        while (a > 0) {
            size_t len = (a >= C) ? C : a;
            a -= len;
            hipMemcpyAsync(stage, slot0 + a, len * sizeof(float),
                           hipMemcpyDeviceToDevice, stream);
            decomp_k<<<(int)((len + 255) / 256), 256, 0, stream>>>(
                slot0 + a, g0b + a, (int)len);
            hipMemcpyAsync(slot1 + a, stage, len * sizeof(float),
                           hipMemcpyDeviceToDevice, stream);
        }
    }
}